// Round 5
// baseline (177.327 us; speedup 1.0000x reference)
//
#include <hip/hip_runtime.h>
#include <math.h>

#define NPG    23
#define HID    48
#define HEADS  4
#define C1     192   // HEADS*HID
#define NFEAT  11
#define GG     1024  // B*T graphs
#define GRUH   64
#define FRAME  96
#define TT     16
#define BB     64

#define HSTR   196   // padded row stride for h/h1 (floats)
#define GSTR   52    // padded row stride for g
#define XSTR   12    // padded x row (11 -> 12, enables b128 reads)

// LDS layout (floats). Region0 reused: x(276) -> als2/ald2(46) -> frame(96).
// H region reused: h(23*196) -> g(23*52) + h2(23*48).
#define OFF_R0   0
#define OFF_ALS  280
#define OFF_ALD  372
#define OFF_H    464
#define OFF_H1   4972
#define LDSF     9480   // 37920 B -> 4 blocks/CU

__device__ __forceinline__ float elu_(float v) {
    return (v > 0.f) ? v : (__expf(v) - 1.f);
}

// ---------------------------------------------------------------------------
// Kernel 1: per-graph GAT1(4h)->ELU->GAT2->ELU->pool->gi0.
// 256 thr/block, 1024 blocks (all co-resident: wall time = block path).
// E' j-tile 4 (h reads /3), F with register-resident W2 slices + shfl
// k-reduction (W2 read exactly once per block), H' j-tile 2.
// ---------------------------------------------------------------------------
__global__ __launch_bounds__(256, 4) void gat_fused(
    const float* __restrict__ x,      // NTOT x 11
    const float* __restrict__ W1,     // 11 x 192
    const float* __restrict__ as1,    // 192
    const float* __restrict__ ad1,    // 192
    const float* __restrict__ b1,     // 192
    const float* __restrict__ W2,     // 192 x 48
    const float* __restrict__ as2,    // 48
    const float* __restrict__ ad2,    // 48
    const float* __restrict__ b2,     // 48
    const float* __restrict__ Wih0,   // 192 x 96
    const float* __restrict__ bih0,   // 192
    float* __restrict__ gi0)          // G x 192
{
    __shared__ float S[LDSF];
    float* s_x    = S + OFF_R0;              // 23 x 12 (padded)
    float* s_als  = S + OFF_ALS;             // [hh*23+n]
    float* s_ald  = S + OFF_ALD;
    float* s_h    = S + OFF_H;               // 23 x 196
    float* s_h1   = S + OFF_H1;              // 23 x 196
    float* s_g    = S + OFF_H;               // overlays h (dead after E')
    float* s_h2   = S + OFF_H + NPG * GSTR;
    float* s_als2 = S + OFF_R0;              // overlays x (dead after B)
    float* s_ald2 = S + OFF_R0 + NPG;
    float* s_frame= S + OFF_R0;              // overlays als2/ald2 (dead after H')

    const int g   = blockIdx.x;
    const int tid = threadIdx.x;

    // ---- load x tile (padded rows) ----
    for (int i = tid; i < NPG * NFEAT; i += 256) {
        const int n = i / NFEAT, k = i % NFEAT;
        s_x[n * XSTR + k] = x[g * NPG * NFEAT + i];
    }
    __syncthreads();

    // ---- B: h = x @ W1, n-tile 5, W1 strip register-resident ----
    if (tid < 240) {
        const int c4 = tid % 48, ng = tid / 48;
        float4 w[NFEAT];
        #pragma unroll
        for (int k = 0; k < NFEAT; k++) w[k] = *(const float4*)(W1 + k * C1 + 4 * c4);
        #pragma unroll
        for (int nn = 0; nn < 5; nn++) {
            const int n = ng * 5 + nn;
            if (n < NPG) {
                const float4 x0 = *(const float4*)(s_x + n * XSTR);
                const float4 x1 = *(const float4*)(s_x + n * XSTR + 4);
                const float4 x2 = *(const float4*)(s_x + n * XSTR + 8);
                float4 acc;
                acc.x = x0.x*w[0].x; acc.y = x0.x*w[0].y; acc.z = x0.x*w[0].z; acc.w = x0.x*w[0].w;
                acc.x += x0.y*w[1].x; acc.y += x0.y*w[1].y; acc.z += x0.y*w[1].z; acc.w += x0.y*w[1].w;
                acc.x += x0.z*w[2].x; acc.y += x0.z*w[2].y; acc.z += x0.z*w[2].z; acc.w += x0.z*w[2].w;
                acc.x += x0.w*w[3].x; acc.y += x0.w*w[3].y; acc.z += x0.w*w[3].z; acc.w += x0.w*w[3].w;
                acc.x += x1.x*w[4].x; acc.y += x1.x*w[4].y; acc.z += x1.x*w[4].z; acc.w += x1.x*w[4].w;
                acc.x += x1.y*w[5].x; acc.y += x1.y*w[5].y; acc.z += x1.y*w[5].z; acc.w += x1.y*w[5].w;
                acc.x += x1.z*w[6].x; acc.y += x1.z*w[6].y; acc.z += x1.z*w[6].z; acc.w += x1.z*w[6].w;
                acc.x += x1.w*w[7].x; acc.y += x1.w*w[7].y; acc.z += x1.w*w[7].z; acc.w += x1.w*w[7].w;
                acc.x += x2.x*w[8].x; acc.y += x2.x*w[8].y; acc.z += x2.x*w[8].z; acc.w += x2.x*w[8].w;
                acc.x += x2.y*w[9].x; acc.y += x2.y*w[9].y; acc.z += x2.y*w[9].z; acc.w += x2.y*w[9].w;
                acc.x += x2.z*w[10].x; acc.y += x2.z*w[10].y; acc.z += x2.z*w[10].z; acc.w += x2.z*w[10].w;
                *(float4*)(s_h + n * HSTR + 4 * c4) = acc;
            }
        }
    }
    __syncthreads();

    // ---- L1: attention logits (184 thr, direct writes) ----
    if (tid < 184) {
        const int which = tid / 92, r = tid % 92, hh = r / NPG, n = r % NPG;
        const float* av = (which ? ad1 : as1) + hh * HID;
        const float* hp = s_h + n * HSTR + hh * HID;
        float s = 0.f;
        #pragma unroll
        for (int k4 = 0; k4 < 12; k4++) {
            const float4 h4 = *(const float4*)(hp + 4 * k4);
            const float4 a4 = *(const float4*)(av + 4 * k4);
            s += h4.x * a4.x + h4.y * a4.y + h4.z * a4.z + h4.w * a4.w;
        }
        if (which) s_ald[hh * NPG + n] = s; else s_als[hh * NPG + n] = s;
    }
    __syncthreads();

    // ---- E': softmax1 + aggregate + b1 + ELU, j-tile 4, 8-float chunks ----
    if (tid < 144) {
        const int q = tid % 6, hh = (tid / 6) % 4, jg = tid / 24;
        const int cb = hh * HID + q * 8;
        float ald[4];
        #pragma unroll
        for (int jj = 0; jj < 4; jj++) {
            const int j = jg * 4 + jj;
            ald[jj] = s_ald[hh * NPG + ((j < NPG) ? j : NPG - 1)];
        }
        float m[4] = {-1e30f, -1e30f, -1e30f, -1e30f};
        #pragma unroll
        for (int i = 0; i < NPG; i++) {
            const float ai = s_als[hh * NPG + i];
            #pragma unroll
            for (int jj = 0; jj < 4; jj++) {
                float e = ai + ald[jj];
                e = (e > 0.f) ? e : 0.2f * e;
                m[jj] = fmaxf(m[jj], e);
            }
        }
        float ss[4] = {0.f, 0.f, 0.f, 0.f};
        float4 a0[4], a1[4];
        #pragma unroll
        for (int jj = 0; jj < 4; jj++) {
            a0[jj] = make_float4(0.f, 0.f, 0.f, 0.f);
            a1[jj] = make_float4(0.f, 0.f, 0.f, 0.f);
        }
        #pragma unroll
        for (int i = 0; i < NPG; i++) {
            const float ai = s_als[hh * NPG + i];
            const float4 hv0 = *(const float4*)(s_h + i * HSTR + cb);
            const float4 hv1 = *(const float4*)(s_h + i * HSTR + cb + 4);
            #pragma unroll
            for (int jj = 0; jj < 4; jj++) {
                float e = ai + ald[jj];
                e = (e > 0.f) ? e : 0.2f * e;
                const float p = __expf(e - m[jj]);
                ss[jj] += p;
                a0[jj].x += p * hv0.x; a0[jj].y += p * hv0.y;
                a0[jj].z += p * hv0.z; a0[jj].w += p * hv0.w;
                a1[jj].x += p * hv1.x; a1[jj].y += p * hv1.y;
                a1[jj].z += p * hv1.z; a1[jj].w += p * hv1.w;
            }
        }
        const float4 bb0 = *(const float4*)(b1 + cb);
        const float4 bb1 = *(const float4*)(b1 + cb + 4);
        #pragma unroll
        for (int jj = 0; jj < 4; jj++) {
            const int j = jg * 4 + jj;
            if (j < NPG) {
                const float inv = 1.f / (ss[jj] + 1e-16f);
                float4 v;
                v.x = elu_(a0[jj].x * inv + bb0.x);
                v.y = elu_(a0[jj].y * inv + bb0.y);
                v.z = elu_(a0[jj].z * inv + bb0.z);
                v.w = elu_(a0[jj].w * inv + bb0.w);
                *(float4*)(s_h1 + j * HSTR + cb) = v;
                v.x = elu_(a1[jj].x * inv + bb1.x);
                v.y = elu_(a1[jj].y * inv + bb1.y);
                v.z = elu_(a1[jj].z * inv + bb1.z);
                v.w = elu_(a1[jj].w * inv + bb1.w);
                *(float4*)(s_h1 + j * HSTR + cb + 4) = v;
            }
        }
    }
    __syncthreads();

    // ---- F: g = h1 @ W2.  thread=(kc 0..15, c4 0..11); W2 12xfloat4 slice
    //      in registers (W2 read ONCE per block); 16-lane shfl k-reduce ----
    if (tid < 192) {
        const int kc = tid & 15, c4 = tid >> 4;
        float4 w[12];
        #pragma unroll
        for (int r = 0; r < 12; r++)
            w[r] = *(const float4*)(W2 + (kc * 12 + r) * HID + 4 * c4);
        const float* h1b = s_h1 + kc * 12;
        for (int n = 0; n < NPG; n++) {
            const float4 hv0 = *(const float4*)(h1b + n * HSTR);
            const float4 hv1 = *(const float4*)(h1b + n * HSTR + 4);
            const float4 hv2 = *(const float4*)(h1b + n * HSTR + 8);
            float4 acc;
            acc.x  = hv0.x*w[0].x;  acc.y  = hv0.x*w[0].y;  acc.z  = hv0.x*w[0].z;  acc.w  = hv0.x*w[0].w;
            acc.x += hv0.y*w[1].x;  acc.y += hv0.y*w[1].y;  acc.z += hv0.y*w[1].z;  acc.w += hv0.y*w[1].w;
            acc.x += hv0.z*w[2].x;  acc.y += hv0.z*w[2].y;  acc.z += hv0.z*w[2].z;  acc.w += hv0.z*w[2].w;
            acc.x += hv0.w*w[3].x;  acc.y += hv0.w*w[3].y;  acc.z += hv0.w*w[3].z;  acc.w += hv0.w*w[3].w;
            acc.x += hv1.x*w[4].x;  acc.y += hv1.x*w[4].y;  acc.z += hv1.x*w[4].z;  acc.w += hv1.x*w[4].w;
            acc.x += hv1.y*w[5].x;  acc.y += hv1.y*w[5].y;  acc.z += hv1.y*w[5].z;  acc.w += hv1.y*w[5].w;
            acc.x += hv1.z*w[6].x;  acc.y += hv1.z*w[6].y;  acc.z += hv1.z*w[6].z;  acc.w += hv1.z*w[6].w;
            acc.x += hv1.w*w[7].x;  acc.y += hv1.w*w[7].y;  acc.z += hv1.w*w[7].z;  acc.w += hv1.w*w[7].w;
            acc.x += hv2.x*w[8].x;  acc.y += hv2.x*w[8].y;  acc.z += hv2.x*w[8].z;  acc.w += hv2.x*w[8].w;
            acc.x += hv2.y*w[9].x;  acc.y += hv2.y*w[9].y;  acc.z += hv2.y*w[9].z;  acc.w += hv2.y*w[9].w;
            acc.x += hv2.z*w[10].x; acc.y += hv2.z*w[10].y; acc.z += hv2.z*w[10].z; acc.w += hv2.z*w[10].w;
            acc.x += hv2.w*w[11].x; acc.y += hv2.w*w[11].y; acc.z += hv2.w*w[11].z; acc.w += hv2.w*w[11].w;
            #pragma unroll
            for (int d = 1; d < 16; d <<= 1) {
                acc.x += __shfl_xor(acc.x, d, 64);
                acc.y += __shfl_xor(acc.y, d, 64);
                acc.z += __shfl_xor(acc.z, d, 64);
                acc.w += __shfl_xor(acc.w, d, 64);
            }
            if (kc == 0) *(float4*)(s_g + n * GSTR + 4 * c4) = acc;
        }
    }
    __syncthreads();

    // ---- L2: layer-2 logits (46 thr) ----
    if (tid < 46) {
        const int which = tid / NPG, n = tid % NPG;
        const float* av = which ? ad2 : as2;
        const float* gp = s_g + n * GSTR;
        float s = 0.f;
        #pragma unroll
        for (int k4 = 0; k4 < 12; k4++) {
            const float4 g4 = *(const float4*)(gp + 4 * k4);
            const float4 a4 = *(const float4*)(av + 4 * k4);
            s += g4.x * a4.x + g4.y * a4.y + g4.z * a4.z + g4.w * a4.w;
        }
        if (which) s_ald2[n] = s; else s_als2[n] = s;
    }
    __syncthreads();

    // ---- H': softmax2 + aggregate + b2 + ELU, j-tile 2 (48 thr) ----
    if (tid < 48) {
        const int q = tid & 3, jp = tid >> 2;
        const int j0 = 2 * jp, j1 = 2 * jp + 1;
        const bool has1 = (j1 < NPG);
        const int cb = q * 12;
        const float ald0 = s_ald2[j0];
        const float ald1 = has1 ? s_ald2[j1] : 0.f;
        float m0 = -1e30f, m1 = -1e30f;
        #pragma unroll
        for (int i = 0; i < NPG; i++) {
            const float ai = s_als2[i];
            float e0 = ai + ald0; e0 = (e0 > 0.f) ? e0 : 0.2f * e0;
            float e1 = ai + ald1; e1 = (e1 > 0.f) ? e1 : 0.2f * e1;
            m0 = fmaxf(m0, e0); m1 = fmaxf(m1, e1);
        }
        float4 acc0[3], acc1[3];
        #pragma unroll
        for (int c = 0; c < 3; c++) {
            acc0[c] = make_float4(0.f, 0.f, 0.f, 0.f);
            acc1[c] = make_float4(0.f, 0.f, 0.f, 0.f);
        }
        float ss0 = 0.f, ss1 = 0.f;
        #pragma unroll
        for (int i = 0; i < NPG; i++) {
            const float ai = s_als2[i];
            float e0 = ai + ald0; e0 = (e0 > 0.f) ? e0 : 0.2f * e0;
            float e1 = ai + ald1; e1 = (e1 > 0.f) ? e1 : 0.2f * e1;
            const float p0 = __expf(e0 - m0); ss0 += p0;
            const float p1 = __expf(e1 - m1); ss1 += p1;
            const float* gp = s_g + i * GSTR + cb;
            #pragma unroll
            for (int c = 0; c < 3; c++) {
                const float4 gv = *(const float4*)(gp + 4 * c);
                acc0[c].x += p0 * gv.x; acc0[c].y += p0 * gv.y;
                acc0[c].z += p0 * gv.z; acc0[c].w += p0 * gv.w;
                acc1[c].x += p1 * gv.x; acc1[c].y += p1 * gv.y;
                acc1[c].z += p1 * gv.z; acc1[c].w += p1 * gv.w;
            }
        }
        const float inv0 = 1.f / (ss0 + 1e-16f);
        const float inv1 = 1.f / (ss1 + 1e-16f);
        #pragma unroll
        for (int c = 0; c < 3; c++) {
            const float4 bb = *(const float4*)(b2 + cb + 4 * c);
            float4 v;
            v.x = elu_(acc0[c].x * inv0 + bb.x);
            v.y = elu_(acc0[c].y * inv0 + bb.y);
            v.z = elu_(acc0[c].z * inv0 + bb.z);
            v.w = elu_(acc0[c].w * inv0 + bb.w);
            *(float4*)(s_h2 + j0 * HID + cb + 4 * c) = v;
            if (has1) {
                v.x = elu_(acc1[c].x * inv1 + bb.x);
                v.y = elu_(acc1[c].y * inv1 + bb.y);
                v.z = elu_(acc1[c].z * inv1 + bb.z);
                v.w = elu_(acc1[c].w * inv1 + bb.w);
                *(float4*)(s_h2 + j1 * HID + cb + 4 * c) = v;
            }
        }
    }
    __syncthreads();

    // ---- pool -> s_frame ----
    if (tid < HID) {
        float sm = 0.f, mx = -1e30f;
        #pragma unroll
        for (int j = 0; j < NPG; j++) {
            const float v = s_h2[j * HID + tid];
            sm += v; mx = fmaxf(mx, v);
        }
        s_frame[tid]       = sm * (1.0f / NPG);
        s_frame[HID + tid] = mx;
    }
    __syncthreads();

    // ---- GI0: gi0 row = frame @ Wih0^T + bih0 ----
    if (tid < C1) {
        float s = bih0[tid];
        const float4* wr = (const float4*)(Wih0 + tid * FRAME);
        const float4* fr = (const float4*)s_frame;
        #pragma unroll
        for (int k4 = 0; k4 < FRAME / 4; k4++) {
            const float4 w = wr[k4];
            const float4 f = fr[k4];
            s += w.x * f.x + w.y * f.y + w.z * f.z + w.w * f.w;
        }
        gi0[g * C1 + tid] = s;
    }
}

// ---------------------------------------------------------------------------
// Kernel 2: 2-layer GRU (T=16) + MLP head. 384 thr/block, 64 blocks.
// row = tid>>1, k-half = tid&1: each thread holds 3 half-rows (96 regs);
// pair shfl_xor(1) completes the dot64s. Layer-1 pipelined one step behind.
// ---------------------------------------------------------------------------
__global__ __launch_bounds__(384) void gru_head(
    const float* __restrict__ gi0g,   // (B*T) x 192 (bih0 already added)
    const float* __restrict__ Whh0,   // 192 x 64
    const float* __restrict__ bhh0,
    const float* __restrict__ Wih1,   // 192 x 64
    const float* __restrict__ bih1,
    const float* __restrict__ Whh1,   // 192 x 64
    const float* __restrict__ bhh1,
    const float* __restrict__ Wh1,    // 64 x 32
    const float* __restrict__ bh1,
    const float* __restrict__ Wh2,    // 32 x 1
    const float* __restrict__ bh2,
    float* __restrict__ out)          // 64
{
    __shared__ float s_gi0[TT * C1];
    __shared__ float s_h0[GRUH], s_h1[GRUH];
    __shared__ float s_gh0[C1], s_gi1[C1], s_gh1[C1];
    __shared__ float s_t1[32];

    const int b = blockIdx.x, tid = threadIdx.x;

    {   // load gi0 (16 x 192 = 768 float4), 2 per thread
        const float4* src = (const float4*)(gi0g + b * TT * C1);
        float4* dst = (float4*)s_gi0;
        dst[tid]       = src[tid];
        dst[tid + 384] = src[tid + 384];
    }
    if (tid < GRUH) { s_h0[tid] = 0.f; s_h1[tid] = 0.f; }

    const int row = tid >> 1, kh = tid & 1;
    float w0[32], w1[32], w2[32];
    {
        const float4* p0 = (const float4*)(Whh0 + row * 64 + kh * 32);
        const float4* p1 = (const float4*)(Wih1 + row * 64 + kh * 32);
        const float4* p2 = (const float4*)(Whh1 + row * 64 + kh * 32);
        #pragma unroll
        for (int k4 = 0; k4 < 8; k4++) {
            const float4 v0 = p0[k4];
            w0[4*k4] = v0.x; w0[4*k4+1] = v0.y; w0[4*k4+2] = v0.z; w0[4*k4+3] = v0.w;
            const float4 v1 = p1[k4];
            w1[4*k4] = v1.x; w1[4*k4+1] = v1.y; w1[4*k4+2] = v1.z; w1[4*k4+3] = v1.w;
            const float4 v2 = p2[k4];
            w2[4*k4] = v2.x; w2[4*k4+1] = v2.y; w2[4*k4+2] = v2.z; w2[4*k4+3] = v2.w;
        }
    }
    const float bh0r = kh ? 0.f : bhh0[row];
    const float bi1r = kh ? 0.f : bih1[row];
    const float bh1r = kh ? 0.f : bhh1[row];
    __syncthreads();

    for (int it = 0; it <= TT; it++) {
        // P1: partial dots over this thread's k-half, then pair-combine
        {
            float s0 = bh0r, s1 = bi1r, s2 = bh1r;
            const float4* h0v = (const float4*)(s_h0 + kh * 32);
            const float4* h1v = (const float4*)(s_h1 + kh * 32);
            #pragma unroll
            for (int k4 = 0; k4 < 8; k4++) {
                const float4 a = h0v[k4];
                const float4 c = h1v[k4];
                s0 += w0[4*k4]*a.x + w0[4*k4+1]*a.y + w0[4*k4+2]*a.z + w0[4*k4+3]*a.w;
                s1 += w1[4*k4]*a.x + w1[4*k4+1]*a.y + w1[4*k4+2]*a.z + w1[4*k4+3]*a.w;
                s2 += w2[4*k4]*c.x + w2[4*k4+1]*c.y + w2[4*k4+2]*c.z + w2[4*k4+3]*c.w;
            }
            s0 += __shfl_xor(s0, 1, 64);
            s1 += __shfl_xor(s1, 1, 64);
            s2 += __shfl_xor(s2, 1, 64);
            if (kh == 0) { s_gh0[row] = s0; s_gi1[row] = s1; s_gh1[row] = s2; }
        }
        __syncthreads();
        // P2: update h0[it] (lanes 0..63) and h1[it-1] (lanes 64..127)
        if (tid < GRUH) {
            if (it < TT) {
                const float ir = s_gi0[it*C1 + tid];
                const float iz = s_gi0[it*C1 + 64 + tid];
                const float in_ = s_gi0[it*C1 + 128 + tid];
                const float hr = s_gh0[tid], hz = s_gh0[64 + tid], hn = s_gh0[128 + tid];
                const float r = 1.f / (1.f + __expf(-(ir + hr)));
                const float z = 1.f / (1.f + __expf(-(iz + hz)));
                const float nx = in_ + r * hn;
                const float e2 = __expf(2.f * nx);
                const float n = (e2 - 1.f) / (e2 + 1.f);
                s_h0[tid] = (1.f - z) * n + z * s_h0[tid];
            }
        } else if (tid < 2 * GRUH) {
            if (it >= 1) {
                const int c = tid - GRUH;
                const float ir = s_gi1[c], iz = s_gi1[64 + c], in_ = s_gi1[128 + c];
                const float hr = s_gh1[c], hz = s_gh1[64 + c], hn = s_gh1[128 + c];
                const float r = 1.f / (1.f + __expf(-(ir + hr)));
                const float z = 1.f / (1.f + __expf(-(iz + hz)));
                const float nx = in_ + r * hn;
                const float e2 = __expf(2.f * nx);
                const float n = (e2 - 1.f) / (e2 + 1.f);
                s_h1[c] = (1.f - z) * n + z * s_h1[c];
            }
        }
        __syncthreads();
    }

    // ---- head: relu(h1[15] @ Wh1 + bh1) @ Wh2 + bh2 ----
    if (tid < 32) {
        float s = bh1[tid];
        #pragma unroll
        for (int k = 0; k < GRUH; k++) s += s_h1[k] * Wh1[k * 32 + tid];
        s_t1[tid] = fmaxf(s, 0.f);
    }
    __syncthreads();
    if (tid == 0) {
        float s = bh2[0];
        #pragma unroll
        for (int k = 0; k < 32; k++) s += s_t1[k] * Wh2[k];
        out[b] = s;
    }
}

extern "C" void kernel_launch(void* const* d_in, const int* in_sizes, int n_in,
                              void* d_out, int out_size, void* d_ws, size_t ws_size,
                              hipStream_t stream) {
    const float* x    = (const float*)d_in[0];
    // d_in[1] = edge_index, d_in[2] = batch : fixed dense structure -> unused
    const float* W1   = (const float*)d_in[3];
    const float* as1  = (const float*)d_in[4];
    const float* ad1  = (const float*)d_in[5];
    const float* b1   = (const float*)d_in[6];
    const float* W2   = (const float*)d_in[7];
    const float* as2  = (const float*)d_in[8];
    const float* ad2  = (const float*)d_in[9];
    const float* b2   = (const float*)d_in[10];
    const float* Wih0 = (const float*)d_in[11];
    const float* Whh0 = (const float*)d_in[12];
    const float* bih0 = (const float*)d_in[13];
    const float* bhh0 = (const float*)d_in[14];
    const float* Wih1 = (const float*)d_in[15];
    const float* Whh1 = (const float*)d_in[16];
    const float* bih1 = (const float*)d_in[17];
    const float* bhh1 = (const float*)d_in[18];
    const float* Wh1  = (const float*)d_in[19];
    const float* bh1  = (const float*)d_in[20];
    const float* Wh2  = (const float*)d_in[21];
    const float* bh2  = (const float*)d_in[22];

    float* out  = (float*)d_out;
    float* gi0  = (float*)d_ws;   // G x 192 fp32 = 786 KB

    hipLaunchKernelGGL(gat_fused, dim3(GG), dim3(256), 0, stream,
                       x, W1, as1, ad1, b1, W2, as2, ad2, b2, Wih0, bih0, gi0);
    hipLaunchKernelGGL(gru_head, dim3(BB), dim3(384), 0, stream,
                       gi0, Whh0, bhh0, Wih1, bih1, Whh1, bhh1,
                       Wh1, bh1, Wh2, bh2, out);
}

// Round 6
// 106.536 us; speedup vs baseline: 1.6645x; 1.6645x over previous
//
#include <hip/hip_runtime.h>
#include <math.h>

#define NPG    23
#define HID    48
#define HEADS  4
#define C1     192   // HEADS*HID
#define NFEAT  11
#define GG     1024  // B*T graphs
#define GRUH   64
#define FRAME  96
#define TT     16
#define BB     64

#define HSTR   196   // padded row stride for h/h1 (floats)
#define GSTR   52    // padded row stride for g

// LDS layout (floats), total 9456 = 37824 B -> 4 blocks/CU
// Region0 reused: x(253) -> als2(23)+ald2(23).
// H region reused: h(23*196) -> g(23*52) + h2(23*48).
#define OFF_X    0
#define OFF_ALS  256
#define OFF_ALD  348
#define OFF_H    440
#define OFF_H1   4948
#define LDSF     9456

__device__ __forceinline__ float elu_(float v) {
    return (v > 0.f) ? v : (__expf(v) - 1.f);
}

// ---------------------------------------------------------------------------
// Kernel 1: per-graph GAT1(4h)->ELU->GAT2->ELU->pool -> frames.
// 256 thr/block, 1024 blocks (4/CU, all co-resident). 6 barrier phases:
//   0 load-x/zero  1 B(+L1 atomics)  2 E'  3 F(+L2 atomics, shfl k-combine)
//   4 H'  5 pool->global
// Every phase register-audited <= ~56 VGPR (launch_bounds(256,4) caps ~64;
// exceeding it spills to scratch = 300+ MB HBM traffic, rounds 3/5 lesson).
// ---------------------------------------------------------------------------
__global__ __launch_bounds__(256, 4) void gat_fused(
    const float* __restrict__ x,      // NTOT x 11
    const float* __restrict__ W1,     // 11 x 192
    const float* __restrict__ as1,    // 192
    const float* __restrict__ ad1,    // 192
    const float* __restrict__ b1,     // 192
    const float* __restrict__ W2,     // 192 x 48
    const float* __restrict__ as2,    // 48
    const float* __restrict__ ad2,    // 48
    const float* __restrict__ b2,     // 48
    float* __restrict__ frames)       // G x 96
{
    __shared__ float S[LDSF];
    float* s_x    = S + OFF_X;
    float* s_als  = S + OFF_ALS;             // [hh*23+n]
    float* s_ald  = S + OFF_ALD;
    float* s_h    = S + OFF_H;               // 23 x 196
    float* s_h1   = S + OFF_H1;              // 23 x 196
    float* s_g    = S + OFF_H;               // overlays h (dead after E')
    float* s_h2   = S + OFF_H + NPG * GSTR;
    float* s_als2 = S + OFF_X;               // overlays x (dead after B)
    float* s_ald2 = S + OFF_X + NPG;

    const int g   = blockIdx.x;
    const int tid = threadIdx.x;

    // ---- phase 0: load x tile, zero als/ald ----
    for (int i = tid; i < NPG * NFEAT; i += 256) s_x[i] = x[g * NPG * NFEAT + i];
    if (tid < 184) s_als[tid] = 0.f;   // covers als+ald (contiguous 92+92)
    __syncthreads();

    // ---- phase 1: B+L1. h = x @ W1 (n-tile 5) + logit partial atomics ----
    if (tid < 240) {
        const int c4 = tid % 48, ng = tid / 48;
        const int hh = c4 / 12;
        const float4 a_s = *(const float4*)(as1 + 4 * c4);
        const float4 a_d = *(const float4*)(ad1 + 4 * c4);
        #pragma unroll
        for (int nn = 0; nn < 5; nn++) {
            const int n = ng * 5 + nn;
            if (n < NPG) {
                float4 acc = make_float4(0.f, 0.f, 0.f, 0.f);
                #pragma unroll
                for (int k = 0; k < NFEAT; k++) {
                    const float4 w = *(const float4*)(W1 + k * C1 + 4 * c4);
                    const float xv = s_x[n * NFEAT + k];
                    acc.x += xv * w.x; acc.y += xv * w.y;
                    acc.z += xv * w.z; acc.w += xv * w.w;
                }
                *(float4*)(s_h + n * HSTR + 4 * c4) = acc;
                atomicAdd(&s_als[hh * NPG + n],
                          acc.x * a_s.x + acc.y * a_s.y + acc.z * a_s.z + acc.w * a_s.w);
                atomicAdd(&s_ald[hh * NPG + n],
                          acc.x * a_d.x + acc.y * a_d.y + acc.z * a_d.z + acc.w * a_d.w);
            }
        }
    }
    __syncthreads();

    // ---- phase 2: E'. softmax1 (alpha in regs) + aggregate + b1 + ELU ----
    if (tid < 184) {
        const int j = tid >> 3, sub = tid & 7;
        const int hh = sub >> 1, half = sub & 1;
        const float ald_j = s_ald[hh * NPG + j];
        float a[NPG];
        float m = -1e30f;
        #pragma unroll
        for (int i = 0; i < NPG; i++) {
            float e = s_als[hh * NPG + i] + ald_j;
            e = (e > 0.f) ? e : 0.2f * e;
            a[i] = e;
            m = fmaxf(m, e);
        }
        float ssum = 0.f;
        #pragma unroll
        for (int i = 0; i < NPG; i++) {
            const float w = __expf(a[i] - m);
            a[i] = w;
            ssum += w;
        }
        const float inv = 1.f / (ssum + 1e-16f);
        const int cb = hh * HID + half * 24;
        #pragma unroll
        for (int c4 = 0; c4 < 6; c4++) {
            float4 acc = make_float4(0.f, 0.f, 0.f, 0.f);
            #pragma unroll
            for (int i = 0; i < NPG; i++) {
                const float4 hv = *(const float4*)(s_h + i * HSTR + cb + 4 * c4);
                acc.x += a[i] * hv.x; acc.y += a[i] * hv.y;
                acc.z += a[i] * hv.z; acc.w += a[i] * hv.w;
            }
            const float4 bb = *(const float4*)(b1 + cb + 4 * c4);
            float4 v;
            v.x = elu_(acc.x * inv + bb.x);
            v.y = elu_(acc.y * inv + bb.y);
            v.z = elu_(acc.z * inv + bb.z);
            v.w = elu_(acc.w * inv + bb.w);
            *(float4*)(s_h1 + j * HSTR + cb + 4 * c4) = v;
        }
    } else if (tid < 184 + 46) {
        s_als2[tid - 184] = 0.f;   // zero als2+ald2 (x region, dead after B)
    }
    __syncthreads();

    // ---- phase 3: F+L2. g = h1 @ W2, k-split 4 (low lane bits) x n-tile 6;
    //      shfl_xor(1,2) combines k-partials; W2 read 147 KB/block.
    //      Logit2 partial atomics folded in. ----
    if (tid < 192) {
        const int kc  = tid & 3;
        const int rem = tid >> 2;
        const int c4  = rem % 12, ng = rem / 12;   // ng 0..3, n-tile 6
        float4 acc[6];
        #pragma unroll
        for (int nn = 0; nn < 6; nn++) acc[nn] = make_float4(0.f, 0.f, 0.f, 0.f);
        #pragma unroll 2
        for (int k4 = 0; k4 < 12; k4++) {
            const int kk = kc * 12 + k4;
            const float* w2p = W2 + (4 * kk) * HID + 4 * c4;
            const float4 r0 = *(const float4*)(w2p);
            const float4 r1 = *(const float4*)(w2p + HID);
            const float4 r2 = *(const float4*)(w2p + 2 * HID);
            const float4 r3 = *(const float4*)(w2p + 3 * HID);
            #pragma unroll
            for (int nn = 0; nn < 6; nn++) {
                int n = ng * 6 + nn; n = (n < NPG) ? n : NPG - 1;
                const float4 hv = *(const float4*)(s_h1 + n * HSTR + 4 * kk);
                acc[nn].x += hv.x*r0.x + hv.y*r1.x + hv.z*r2.x + hv.w*r3.x;
                acc[nn].y += hv.x*r0.y + hv.y*r1.y + hv.z*r2.y + hv.w*r3.y;
                acc[nn].z += hv.x*r0.z + hv.y*r1.z + hv.z*r2.z + hv.w*r3.z;
                acc[nn].w += hv.x*r0.w + hv.y*r1.w + hv.z*r2.w + hv.w*r3.w;
            }
        }
        // combine the 4 k-partials (lanes differing in bits 0..1)
        #pragma unroll
        for (int nn = 0; nn < 6; nn++) {
            float4 a = acc[nn];
            a.x += __shfl_xor(a.x, 1); a.x += __shfl_xor(a.x, 2);
            a.y += __shfl_xor(a.y, 1); a.y += __shfl_xor(a.y, 2);
            a.z += __shfl_xor(a.z, 1); a.z += __shfl_xor(a.z, 2);
            a.w += __shfl_xor(a.w, 1); a.w += __shfl_xor(a.w, 2);
            acc[nn] = a;
        }
        if (kc == 0) {
            const float4 a_s = *(const float4*)(as2 + 4 * c4);
            const float4 a_d = *(const float4*)(ad2 + 4 * c4);
            #pragma unroll
            for (int nn = 0; nn < 6; nn++) {
                const int n = ng * 6 + nn;
                if (n < NPG) {
                    *(float4*)(s_g + n * GSTR + 4 * c4) = acc[nn];
                    atomicAdd(&s_als2[n],
                              acc[nn].x*a_s.x + acc[nn].y*a_s.y + acc[nn].z*a_s.z + acc[nn].w*a_s.w);
                    atomicAdd(&s_ald2[n],
                              acc[nn].x*a_d.x + acc[nn].y*a_d.y + acc[nn].z*a_d.z + acc[nn].w*a_d.w);
                }
            }
        }
    }
    __syncthreads();

    // ---- phase 4: H'. softmax2 + aggregate + b2 + ELU, j-tile 2 ----
    if (tid < 48) {
        const int q = tid & 3, jp = tid >> 2;
        const int j0 = 2 * jp, j1 = 2 * jp + 1;
        const bool has1 = (j1 < NPG);
        const int cb = q * 12;
        const float ald0 = s_ald2[j0];
        const float ald1 = has1 ? s_ald2[j1] : 0.f;
        float m0 = -1e30f, m1 = -1e30f;
        #pragma unroll
        for (int i = 0; i < NPG; i++) {
            const float ai = s_als2[i];
            float e0 = ai + ald0; e0 = (e0 > 0.f) ? e0 : 0.2f * e0;
            float e1 = ai + ald1; e1 = (e1 > 0.f) ? e1 : 0.2f * e1;
            m0 = fmaxf(m0, e0); m1 = fmaxf(m1, e1);
        }
        float4 acc0[3], acc1[3];
        #pragma unroll
        for (int c = 0; c < 3; c++) {
            acc0[c] = make_float4(0.f, 0.f, 0.f, 0.f);
            acc1[c] = make_float4(0.f, 0.f, 0.f, 0.f);
        }
        float ss0 = 0.f, ss1 = 0.f;
        #pragma unroll
        for (int i = 0; i < NPG; i++) {
            const float ai = s_als2[i];
            float e0 = ai + ald0; e0 = (e0 > 0.f) ? e0 : 0.2f * e0;
            float e1 = ai + ald1; e1 = (e1 > 0.f) ? e1 : 0.2f * e1;
            const float p0 = __expf(e0 - m0); ss0 += p0;
            const float p1 = __expf(e1 - m1); ss1 += p1;
            const float* gp = s_g + i * GSTR + cb;
            #pragma unroll
            for (int c = 0; c < 3; c++) {
                const float4 gv = *(const float4*)(gp + 4 * c);
                acc0[c].x += p0 * gv.x; acc0[c].y += p0 * gv.y;
                acc0[c].z += p0 * gv.z; acc0[c].w += p0 * gv.w;
                acc1[c].x += p1 * gv.x; acc1[c].y += p1 * gv.y;
                acc1[c].z += p1 * gv.z; acc1[c].w += p1 * gv.w;
            }
        }
        const float inv0 = 1.f / (ss0 + 1e-16f);
        const float inv1 = 1.f / (ss1 + 1e-16f);
        #pragma unroll
        for (int c = 0; c < 3; c++) {
            const float4 bb = *(const float4*)(b2 + cb + 4 * c);
            float4 v;
            v.x = elu_(acc0[c].x * inv0 + bb.x);
            v.y = elu_(acc0[c].y * inv0 + bb.y);
            v.z = elu_(acc0[c].z * inv0 + bb.z);
            v.w = elu_(acc0[c].w * inv0 + bb.w);
            *(float4*)(s_h2 + j0 * HID + cb + 4 * c) = v;
            if (has1) {
                v.x = elu_(acc1[c].x * inv1 + bb.x);
                v.y = elu_(acc1[c].y * inv1 + bb.y);
                v.z = elu_(acc1[c].z * inv1 + bb.z);
                v.w = elu_(acc1[c].w * inv1 + bb.w);
                *(float4*)(s_h2 + j1 * HID + cb + 4 * c) = v;
            }
        }
    }
    __syncthreads();

    // ---- phase 5: pool -> global frames ----
    if (tid < HID) {
        float sm = 0.f, mx = -1e30f;
        #pragma unroll
        for (int j = 0; j < NPG; j++) {
            const float v = s_h2[j * HID + tid];
            sm += v; mx = fmaxf(mx, v);
        }
        frames[g * FRAME + tid]       = sm * (1.0f / NPG);
        frames[g * FRAME + HID + tid] = mx;
    }
}

// ---------------------------------------------------------------------------
// Kernel 2: gi0 GEMM preamble + 2-layer GRU (T=16) + MLP head.
// 384 thr/block, 64 blocks. gi0 = frames @ Wih0^T computed here so Wih0 is
// read 64x (4.7 MB) instead of 1024x (75 MB). Recurrent loop: round-5 proven
// k-split-2 pipeline (row=tid>>1, kh=tid&1, pair shfl; layer-1 one step
// behind layer-0; 2 barriers/step).
// ---------------------------------------------------------------------------
__global__ __launch_bounds__(384) void gru_head(
    const float* __restrict__ frames, // G x 96
    const float* __restrict__ Wih0,   // 192 x 96
    const float* __restrict__ bih0,   // 192
    const float* __restrict__ Whh0,   // 192 x 64
    const float* __restrict__ bhh0,
    const float* __restrict__ Wih1,   // 192 x 64
    const float* __restrict__ bih1,
    const float* __restrict__ Whh1,   // 192 x 64
    const float* __restrict__ bhh1,
    const float* __restrict__ Wh1,    // 64 x 32
    const float* __restrict__ bh1,
    const float* __restrict__ Wh2,    // 32 x 1
    const float* __restrict__ bh2,
    float* __restrict__ out)          // 64
{
    __shared__ float s_f[TT * FRAME];    // 1536
    __shared__ float s_gi0[TT * C1];     // 3072
    __shared__ float s_h0[GRUH], s_h1[GRUH];
    __shared__ float s_gh0[C1], s_gi1[C1], s_gh1[C1];
    __shared__ float s_t1[32];

    const int b = blockIdx.x, tid = threadIdx.x;

    {   // load this sequence's frames: 16x96 = 384 float4, 1 per thread
        const float4* src = (const float4*)(frames + b * TT * FRAME);
        ((float4*)s_f)[tid] = src[tid];
    }
    if (tid < GRUH) { s_h0[tid] = 0.f; s_h1[tid] = 0.f; }
    __syncthreads();

    // ---- gi0 preamble: gi0[t][c] = frame[t] . Wih0[c] + bih0[c] ----
    {
        const int c = tid % C1, tp = tid / C1;    // tp 0..1, 8 t's each
        float accg[8];
        const float b0 = bih0[c];
        #pragma unroll
        for (int tt = 0; tt < 8; tt++) accg[tt] = b0;
        const float4* wr = (const float4*)(Wih0 + c * FRAME);
        const float4* f4 = (const float4*)s_f;
        #pragma unroll 4
        for (int k4 = 0; k4 < FRAME / 4; k4++) {
            const float4 w = wr[k4];
            #pragma unroll
            for (int tt = 0; tt < 8; tt++) {
                const float4 f = f4[(tt * 2 + tp) * (FRAME / 4) + k4];
                accg[tt] += w.x * f.x + w.y * f.y + w.z * f.z + w.w * f.w;
            }
        }
        #pragma unroll
        for (int tt = 0; tt < 8; tt++) s_gi0[(tt * 2 + tp) * C1 + c] = accg[tt];
    }

    // ---- register-resident recurrent half-rows (3 x 32 floats) ----
    const int row = tid >> 1, kh = tid & 1;
    float w0[32], w1[32], w2[32];
    {
        const float4* p0 = (const float4*)(Whh0 + row * 64 + kh * 32);
        const float4* p1 = (const float4*)(Wih1 + row * 64 + kh * 32);
        const float4* p2 = (const float4*)(Whh1 + row * 64 + kh * 32);
        #pragma unroll
        for (int k4 = 0; k4 < 8; k4++) {
            const float4 v0 = p0[k4];
            w0[4*k4] = v0.x; w0[4*k4+1] = v0.y; w0[4*k4+2] = v0.z; w0[4*k4+3] = v0.w;
            const float4 v1 = p1[k4];
            w1[4*k4] = v1.x; w1[4*k4+1] = v1.y; w1[4*k4+2] = v1.z; w1[4*k4+3] = v1.w;
            const float4 v2 = p2[k4];
            w2[4*k4] = v2.x; w2[4*k4+1] = v2.y; w2[4*k4+2] = v2.z; w2[4*k4+3] = v2.w;
        }
    }
    const float bh0r = kh ? 0.f : bhh0[row];
    const float bi1r = kh ? 0.f : bih1[row];
    const float bh1r = kh ? 0.f : bhh1[row];
    __syncthreads();   // covers gi0 writes

    for (int it = 0; it <= TT; it++) {
        // P1: partial dots over this thread's k-half, pair-combine via shfl
        {
            float s0 = bh0r, s1 = bi1r, s2 = bh1r;
            const float4* h0v = (const float4*)(s_h0 + kh * 32);
            const float4* h1v = (const float4*)(s_h1 + kh * 32);
            #pragma unroll
            for (int k4 = 0; k4 < 8; k4++) {
                const float4 a = h0v[k4];
                const float4 c = h1v[k4];
                s0 += w0[4*k4]*a.x + w0[4*k4+1]*a.y + w0[4*k4+2]*a.z + w0[4*k4+3]*a.w;
                s1 += w1[4*k4]*a.x + w1[4*k4+1]*a.y + w1[4*k4+2]*a.z + w1[4*k4+3]*a.w;
                s2 += w2[4*k4]*c.x + w2[4*k4+1]*c.y + w2[4*k4+2]*c.z + w2[4*k4+3]*c.w;
            }
            s0 += __shfl_xor(s0, 1, 64);
            s1 += __shfl_xor(s1, 1, 64);
            s2 += __shfl_xor(s2, 1, 64);
            if (kh == 0) { s_gh0[row] = s0; s_gi1[row] = s1; s_gh1[row] = s2; }
        }
        __syncthreads();
        // P2: update h0[it] (lanes 0..63) and h1[it-1] (lanes 64..127)
        if (tid < GRUH) {
            if (it < TT) {
                const float ir = s_gi0[it*C1 + tid];
                const float iz = s_gi0[it*C1 + 64 + tid];
                const float in_ = s_gi0[it*C1 + 128 + tid];
                const float hr = s_gh0[tid], hz = s_gh0[64 + tid], hn = s_gh0[128 + tid];
                const float r = 1.f / (1.f + __expf(-(ir + hr)));
                const float z = 1.f / (1.f + __expf(-(iz + hz)));
                const float nx = in_ + r * hn;
                const float e2 = __expf(2.f * nx);
                const float n = (e2 - 1.f) / (e2 + 1.f);
                s_h0[tid] = (1.f - z) * n + z * s_h0[tid];
            }
        } else if (tid < 2 * GRUH) {
            if (it >= 1) {
                const int c = tid - GRUH;
                const float ir = s_gi1[c], iz = s_gi1[64 + c], in_ = s_gi1[128 + c];
                const float hr = s_gh1[c], hz = s_gh1[64 + c], hn = s_gh1[128 + c];
                const float r = 1.f / (1.f + __expf(-(ir + hr)));
                const float z = 1.f / (1.f + __expf(-(iz + hz)));
                const float nx = in_ + r * hn;
                const float e2 = __expf(2.f * nx);
                const float n = (e2 - 1.f) / (e2 + 1.f);
                s_h1[c] = (1.f - z) * n + z * s_h1[c];
            }
        }
        __syncthreads();
    }

    // ---- head: relu(h1[15] @ Wh1 + bh1) @ Wh2 + bh2 ----
    if (tid < 32) {
        float s = bh1[tid];
        #pragma unroll
        for (int k = 0; k < GRUH; k++) s += s_h1[k] * Wh1[k * 32 + tid];
        s_t1[tid] = fmaxf(s, 0.f);
    }
    __syncthreads();
    if (tid == 0) {
        float s = bh2[0];
        #pragma unroll
        for (int k = 0; k < 32; k++) s += s_t1[k] * Wh2[k];
        out[b] = s;
    }
}

extern "C" void kernel_launch(void* const* d_in, const int* in_sizes, int n_in,
                              void* d_out, int out_size, void* d_ws, size_t ws_size,
                              hipStream_t stream) {
    const float* x    = (const float*)d_in[0];
    // d_in[1] = edge_index, d_in[2] = batch : fixed dense structure -> unused
    const float* W1   = (const float*)d_in[3];
    const float* as1  = (const float*)d_in[4];
    const float* ad1  = (const float*)d_in[5];
    const float* b1   = (const float*)d_in[6];
    const float* W2   = (const float*)d_in[7];
    const float* as2  = (const float*)d_in[8];
    const float* ad2  = (const float*)d_in[9];
    const float* b2   = (const float*)d_in[10];
    const float* Wih0 = (const float*)d_in[11];
    const float* Whh0 = (const float*)d_in[12];
    const float* bih0 = (const float*)d_in[13];
    const float* bhh0 = (const float*)d_in[14];
    const float* Wih1 = (const float*)d_in[15];
    const float* Whh1 = (const float*)d_in[16];
    const float* bih1 = (const float*)d_in[17];
    const float* bhh1 = (const float*)d_in[18];
    const float* Wh1  = (const float*)d_in[19];
    const float* bh1  = (const float*)d_in[20];
    const float* Wh2  = (const float*)d_in[21];
    const float* bh2  = (const float*)d_in[22];

    float* out    = (float*)d_out;
    float* frames = (float*)d_ws;   // G x 96 fp32 = 393 KB

    hipLaunchKernelGGL(gat_fused, dim3(GG), dim3(256), 0, stream,
                       x, W1, as1, ad1, b1, W2, as2, ad2, b2, frames);
    hipLaunchKernelGGL(gru_head, dim3(BB), dim3(384), 0, stream,
                       frames, Wih0, bih0, Whh0, bhh0, Wih1, bih1, Whh1, bhh1,
                       Wh1, bh1, Wh2, bh2, out);
}

// Round 7
// 92.525 us; speedup vs baseline: 1.9165x; 1.1514x over previous
//
#include <hip/hip_runtime.h>
#include <math.h>

#define NPG    23
#define HID    48
#define HEADS  4
#define C1     192   // HEADS*HID
#define NFEAT  11
#define GG     1024  // B*T graphs
#define GRUH   64
#define FRAME  96
#define TT     16
#define BB     64

#define HSTR   196   // padded row stride for h/h1 (floats)
#define GSTR   52    // padded row stride for g

// LDS layout (floats), total 9456 = 37824 B -> 4 blocks/CU
// Region0 reused: x(253) -> als2(23)+ald2(23).
// H region reused: h(23*196) -> g(23*52) + h2(23*48).
#define OFF_X    0
#define OFF_ALS  256
#define OFF_ALD  348
#define OFF_H    440
#define OFF_H1   4948
#define LDSF     9456

__device__ __forceinline__ float elu_(float v) {
    return (v > 0.f) ? v : (__expf(v) - 1.f);
}

// ---------------------------------------------------------------------------
// Kernel 1: per-graph GAT1(4h)->ELU->GAT2->ELU->pool -> frames.
// 256 thr/block, 1024 blocks (4/CU via 37.9KB LDS, all co-resident).
// NOTE: __launch_bounds__(256) WITHOUT a min-waves clause. (256,4) imposed a
// ~64-VGPR ceiling (observed rounds 2-6) and spilled any phase >64 live regs
// to scratch (68-300 MB HBM traffic). 4 waves/SIMD is sustained up to 128
// VGPR, so the bound was pure downside.
// ---------------------------------------------------------------------------
__global__ __launch_bounds__(256) void gat_fused(
    const float* __restrict__ x,      // NTOT x 11
    const float* __restrict__ W1,     // 11 x 192
    const float* __restrict__ as1,    // 192
    const float* __restrict__ ad1,    // 192
    const float* __restrict__ b1,     // 192
    const float* __restrict__ W2,     // 192 x 48
    const float* __restrict__ as2,    // 48
    const float* __restrict__ ad2,    // 48
    const float* __restrict__ b2,     // 48
    float* __restrict__ frames)       // G x 96
{
    __shared__ float S[LDSF];
    float* s_x    = S + OFF_X;
    float* s_als  = S + OFF_ALS;             // [hh*23+n]
    float* s_ald  = S + OFF_ALD;
    float* s_h    = S + OFF_H;               // 23 x 196
    float* s_h1   = S + OFF_H1;              // 23 x 196
    float* s_g    = S + OFF_H;               // overlays h (dead after E')
    float* s_h2   = S + OFF_H + NPG * GSTR;
    float* s_als2 = S + OFF_X;               // overlays x (dead after B)
    float* s_ald2 = S + OFF_X + NPG;

    const int g   = blockIdx.x;
    const int tid = threadIdx.x;

    // ---- phase 0: load x tile, zero als/ald ----
    for (int i = tid; i < NPG * NFEAT; i += 256) s_x[i] = x[g * NPG * NFEAT + i];
    if (tid < 184) s_als[tid] = 0.f;   // covers als+ald (contiguous 92+92)
    __syncthreads();

    // ---- phase 1: B+L1. h = x @ W1 (n-tile 5) + logit partial atomics ----
    if (tid < 240) {
        const int c4 = tid % 48, ng = tid / 48;
        const int hh = c4 / 12;
        const float4 a_s = *(const float4*)(as1 + 4 * c4);
        const float4 a_d = *(const float4*)(ad1 + 4 * c4);
        #pragma unroll
        for (int nn = 0; nn < 5; nn++) {
            const int n = ng * 5 + nn;
            if (n < NPG) {
                float4 acc = make_float4(0.f, 0.f, 0.f, 0.f);
                #pragma unroll
                for (int k = 0; k < NFEAT; k++) {
                    const float4 w = *(const float4*)(W1 + k * C1 + 4 * c4);
                    const float xv = s_x[n * NFEAT + k];
                    acc.x += xv * w.x; acc.y += xv * w.y;
                    acc.z += xv * w.z; acc.w += xv * w.w;
                }
                *(float4*)(s_h + n * HSTR + 4 * c4) = acc;
                atomicAdd(&s_als[hh * NPG + n],
                          acc.x * a_s.x + acc.y * a_s.y + acc.z * a_s.z + acc.w * a_s.w);
                atomicAdd(&s_ald[hh * NPG + n],
                          acc.x * a_d.x + acc.y * a_d.y + acc.z * a_d.z + acc.w * a_d.w);
            }
        }
    }
    __syncthreads();

    // ---- phase 2: E'. softmax1 (alpha in regs) + aggregate + b1 + ELU ----
    if (tid < 184) {
        const int j = tid >> 3, sub = tid & 7;
        const int hh = sub >> 1, half = sub & 1;
        const float ald_j = s_ald[hh * NPG + j];
        float a[NPG];
        float m = -1e30f;
        #pragma unroll
        for (int i = 0; i < NPG; i++) {
            float e = s_als[hh * NPG + i] + ald_j;
            e = (e > 0.f) ? e : 0.2f * e;
            a[i] = e;
            m = fmaxf(m, e);
        }
        float ssum = 0.f;
        #pragma unroll
        for (int i = 0; i < NPG; i++) {
            const float w = __expf(a[i] - m);
            a[i] = w;
            ssum += w;
        }
        const float inv = 1.f / (ssum + 1e-16f);
        const int cb = hh * HID + half * 24;
        #pragma unroll
        for (int c4 = 0; c4 < 6; c4++) {
            float4 acc = make_float4(0.f, 0.f, 0.f, 0.f);
            #pragma unroll
            for (int i = 0; i < NPG; i++) {
                const float4 hv = *(const float4*)(s_h + i * HSTR + cb + 4 * c4);
                acc.x += a[i] * hv.x; acc.y += a[i] * hv.y;
                acc.z += a[i] * hv.z; acc.w += a[i] * hv.w;
            }
            const float4 bb = *(const float4*)(b1 + cb + 4 * c4);
            float4 v;
            v.x = elu_(acc.x * inv + bb.x);
            v.y = elu_(acc.y * inv + bb.y);
            v.z = elu_(acc.z * inv + bb.z);
            v.w = elu_(acc.w * inv + bb.w);
            *(float4*)(s_h1 + j * HSTR + cb + 4 * c4) = v;
        }
    } else if (tid < 184 + 46) {
        s_als2[tid - 184] = 0.f;   // zero als2+ald2 (x region, dead after B)
    }
    __syncthreads();

    // ---- phase 3: F+L2. g = h1 @ W2, k-split 4 (low lane bits) x n-tile 6;
    //      shfl_xor(1,2) combines k-partials; W2 read 147 KB/block.
    //      Logit2 partial atomics folded in. ----
    if (tid < 192) {
        const int kc  = tid & 3;
        const int rem = tid >> 2;
        const int c4  = rem % 12, ng = rem / 12;   // ng 0..3, n-tile 6
        float4 acc[6];
        #pragma unroll
        for (int nn = 0; nn < 6; nn++) acc[nn] = make_float4(0.f, 0.f, 0.f, 0.f);
        #pragma unroll 2
        for (int k4 = 0; k4 < 12; k4++) {
            const int kk = kc * 12 + k4;
            const float* w2p = W2 + (4 * kk) * HID + 4 * c4;
            const float4 r0 = *(const float4*)(w2p);
            const float4 r1 = *(const float4*)(w2p + HID);
            const float4 r2 = *(const float4*)(w2p + 2 * HID);
            const float4 r3 = *(const float4*)(w2p + 3 * HID);
            #pragma unroll
            for (int nn = 0; nn < 6; nn++) {
                int n = ng * 6 + nn; n = (n < NPG) ? n : NPG - 1;
                const float4 hv = *(const float4*)(s_h1 + n * HSTR + 4 * kk);
                acc[nn].x += hv.x*r0.x + hv.y*r1.x + hv.z*r2.x + hv.w*r3.x;
                acc[nn].y += hv.x*r0.y + hv.y*r1.y + hv.z*r2.y + hv.w*r3.y;
                acc[nn].z += hv.x*r0.z + hv.y*r1.z + hv.z*r2.z + hv.w*r3.z;
                acc[nn].w += hv.x*r0.w + hv.y*r1.w + hv.z*r2.w + hv.w*r3.w;
            }
        }
        // combine the 4 k-partials (lanes differing in bits 0..1)
        #pragma unroll
        for (int nn = 0; nn < 6; nn++) {
            float4 a = acc[nn];
            a.x += __shfl_xor(a.x, 1); a.x += __shfl_xor(a.x, 2);
            a.y += __shfl_xor(a.y, 1); a.y += __shfl_xor(a.y, 2);
            a.z += __shfl_xor(a.z, 1); a.z += __shfl_xor(a.z, 2);
            a.w += __shfl_xor(a.w, 1); a.w += __shfl_xor(a.w, 2);
            acc[nn] = a;
        }
        if (kc == 0) {
            const float4 a_s = *(const float4*)(as2 + 4 * c4);
            const float4 a_d = *(const float4*)(ad2 + 4 * c4);
            #pragma unroll
            for (int nn = 0; nn < 6; nn++) {
                const int n = ng * 6 + nn;
                if (n < NPG) {
                    *(float4*)(s_g + n * GSTR + 4 * c4) = acc[nn];
                    atomicAdd(&s_als2[n],
                              acc[nn].x*a_s.x + acc[nn].y*a_s.y + acc[nn].z*a_s.z + acc[nn].w*a_s.w);
                    atomicAdd(&s_ald2[n],
                              acc[nn].x*a_d.x + acc[nn].y*a_d.y + acc[nn].z*a_d.z + acc[nn].w*a_d.w);
                }
            }
        }
    }
    __syncthreads();

    // ---- phase 4: H'. softmax2 + aggregate + b2 + ELU, j-tile 2 ----
    if (tid < 48) {
        const int q = tid & 3, jp = tid >> 2;
        const int j0 = 2 * jp, j1 = 2 * jp + 1;
        const bool has1 = (j1 < NPG);
        const int cb = q * 12;
        const float ald0 = s_ald2[j0];
        const float ald1 = has1 ? s_ald2[j1] : 0.f;
        float m0 = -1e30f, m1 = -1e30f;
        #pragma unroll
        for (int i = 0; i < NPG; i++) {
            const float ai = s_als2[i];
            float e0 = ai + ald0; e0 = (e0 > 0.f) ? e0 : 0.2f * e0;
            float e1 = ai + ald1; e1 = (e1 > 0.f) ? e1 : 0.2f * e1;
            m0 = fmaxf(m0, e0); m1 = fmaxf(m1, e1);
        }
        float4 acc0[3], acc1[3];
        #pragma unroll
        for (int c = 0; c < 3; c++) {
            acc0[c] = make_float4(0.f, 0.f, 0.f, 0.f);
            acc1[c] = make_float4(0.f, 0.f, 0.f, 0.f);
        }
        float ss0 = 0.f, ss1 = 0.f;
        #pragma unroll
        for (int i = 0; i < NPG; i++) {
            const float ai = s_als2[i];
            float e0 = ai + ald0; e0 = (e0 > 0.f) ? e0 : 0.2f * e0;
            float e1 = ai + ald1; e1 = (e1 > 0.f) ? e1 : 0.2f * e1;
            const float p0 = __expf(e0 - m0); ss0 += p0;
            const float p1 = __expf(e1 - m1); ss1 += p1;
            const float* gp = s_g + i * GSTR + cb;
            #pragma unroll
            for (int c = 0; c < 3; c++) {
                const float4 gv = *(const float4*)(gp + 4 * c);
                acc0[c].x += p0 * gv.x; acc0[c].y += p0 * gv.y;
                acc0[c].z += p0 * gv.z; acc0[c].w += p0 * gv.w;
                acc1[c].x += p1 * gv.x; acc1[c].y += p1 * gv.y;
                acc1[c].z += p1 * gv.z; acc1[c].w += p1 * gv.w;
            }
        }
        const float inv0 = 1.f / (ss0 + 1e-16f);
        const float inv1 = 1.f / (ss1 + 1e-16f);
        #pragma unroll
        for (int c = 0; c < 3; c++) {
            const float4 bb = *(const float4*)(b2 + cb + 4 * c);
            float4 v;
            v.x = elu_(acc0[c].x * inv0 + bb.x);
            v.y = elu_(acc0[c].y * inv0 + bb.y);
            v.z = elu_(acc0[c].z * inv0 + bb.z);
            v.w = elu_(acc0[c].w * inv0 + bb.w);
            *(float4*)(s_h2 + j0 * HID + cb + 4 * c) = v;
            if (has1) {
                v.x = elu_(acc1[c].x * inv1 + bb.x);
                v.y = elu_(acc1[c].y * inv1 + bb.y);
                v.z = elu_(acc1[c].z * inv1 + bb.z);
                v.w = elu_(acc1[c].w * inv1 + bb.w);
                *(float4*)(s_h2 + j1 * HID + cb + 4 * c) = v;
            }
        }
    }
    __syncthreads();

    // ---- phase 5: pool -> global frames ----
    if (tid < HID) {
        float sm = 0.f, mx = -1e30f;
        #pragma unroll
        for (int j = 0; j < NPG; j++) {
            const float v = s_h2[j * HID + tid];
            sm += v; mx = fmaxf(mx, v);
        }
        frames[g * FRAME + tid]       = sm * (1.0f / NPG);
        frames[g * FRAME + HID + tid] = mx;
    }
}

// ---------------------------------------------------------------------------
// Kernel 2: gi0 GEMM preamble + 2-layer GRU (T=16) + MLP head.
// 384 thr/block, 64 blocks. gi0 = frames @ Wih0^T computed here so Wih0 is
// read 64x (4.7 MB) instead of 1024x (75 MB). Recurrent loop: k-split-2
// pipeline (row=tid>>1, kh=tid&1, pair shfl; layer-1 one step behind
// layer-0; 2 barriers/step).
// ---------------------------------------------------------------------------
__global__ __launch_bounds__(384) void gru_head(
    const float* __restrict__ frames, // G x 96
    const float* __restrict__ Wih0,   // 192 x 96
    const float* __restrict__ bih0,   // 192
    const float* __restrict__ Whh0,   // 192 x 64
    const float* __restrict__ bhh0,
    const float* __restrict__ Wih1,   // 192 x 64
    const float* __restrict__ bih1,
    const float* __restrict__ Whh1,   // 192 x 64
    const float* __restrict__ bhh1,
    const float* __restrict__ Wh1,    // 64 x 32
    const float* __restrict__ bh1,
    const float* __restrict__ Wh2,    // 32 x 1
    const float* __restrict__ bh2,
    float* __restrict__ out)          // 64
{
    __shared__ float s_f[TT * FRAME];    // 1536
    __shared__ float s_gi0[TT * C1];     // 3072
    __shared__ float s_h0[GRUH], s_h1[GRUH];
    __shared__ float s_gh0[C1], s_gi1[C1], s_gh1[C1];
    __shared__ float s_t1[32];

    const int b = blockIdx.x, tid = threadIdx.x;

    {   // load this sequence's frames: 16x96 = 384 float4, 1 per thread
        const float4* src = (const float4*)(frames + b * TT * FRAME);
        ((float4*)s_f)[tid] = src[tid];
    }
    if (tid < GRUH) { s_h0[tid] = 0.f; s_h1[tid] = 0.f; }
    __syncthreads();

    // ---- gi0 preamble: gi0[t][c] = frame[t] . Wih0[c] + bih0[c] ----
    {
        const int c = tid % C1, tp = tid / C1;    // tp 0..1, 8 t's each
        float accg[8];
        const float b0 = bih0[c];
        #pragma unroll
        for (int tt = 0; tt < 8; tt++) accg[tt] = b0;
        const float4* wr = (const float4*)(Wih0 + c * FRAME);
        const float4* f4 = (const float4*)s_f;
        #pragma unroll 4
        for (int k4 = 0; k4 < FRAME / 4; k4++) {
            const float4 w = wr[k4];
            #pragma unroll
            for (int tt = 0; tt < 8; tt++) {
                const float4 f = f4[(tt * 2 + tp) * (FRAME / 4) + k4];
                accg[tt] += w.x * f.x + w.y * f.y + w.z * f.z + w.w * f.w;
            }
        }
        #pragma unroll
        for (int tt = 0; tt < 8; tt++) s_gi0[(tt * 2 + tp) * C1 + c] = accg[tt];
    }

    // ---- register-resident recurrent half-rows (3 x 32 floats) ----
    const int row = tid >> 1, kh = tid & 1;
    float w0[32], w1[32], w2[32];
    {
        const float4* p0 = (const float4*)(Whh0 + row * 64 + kh * 32);
        const float4* p1 = (const float4*)(Wih1 + row * 64 + kh * 32);
        const float4* p2 = (const float4*)(Whh1 + row * 64 + kh * 32);
        #pragma unroll
        for (int k4 = 0; k4 < 8; k4++) {
            const float4 v0 = p0[k4];
            w0[4*k4] = v0.x; w0[4*k4+1] = v0.y; w0[4*k4+2] = v0.z; w0[4*k4+3] = v0.w;
            const float4 v1 = p1[k4];
            w1[4*k4] = v1.x; w1[4*k4+1] = v1.y; w1[4*k4+2] = v1.z; w1[4*k4+3] = v1.w;
            const float4 v2 = p2[k4];
            w2[4*k4] = v2.x; w2[4*k4+1] = v2.y; w2[4*k4+2] = v2.z; w2[4*k4+3] = v2.w;
        }
    }
    const float bh0r = kh ? 0.f : bhh0[row];
    const float bi1r = kh ? 0.f : bih1[row];
    const float bh1r = kh ? 0.f : bhh1[row];
    __syncthreads();   // covers gi0 writes

    for (int it = 0; it <= TT; it++) {
        // P1: partial dots over this thread's k-half, pair-combine via shfl
        {
            float s0 = bh0r, s1 = bi1r, s2 = bh1r;
            const float4* h0v = (const float4*)(s_h0 + kh * 32);
            const float4* h1v = (const float4*)(s_h1 + kh * 32);
            #pragma unroll
            for (int k4 = 0; k4 < 8; k4++) {
                const float4 a = h0v[k4];
                const float4 c = h1v[k4];
                s0 += w0[4*k4]*a.x + w0[4*k4+1]*a.y + w0[4*k4+2]*a.z + w0[4*k4+3]*a.w;
                s1 += w1[4*k4]*a.x + w1[4*k4+1]*a.y + w1[4*k4+2]*a.z + w1[4*k4+3]*a.w;
                s2 += w2[4*k4]*c.x + w2[4*k4+1]*c.y + w2[4*k4+2]*c.z + w2[4*k4+3]*c.w;
            }
            s0 += __shfl_xor(s0, 1, 64);
            s1 += __shfl_xor(s1, 1, 64);
            s2 += __shfl_xor(s2, 1, 64);
            if (kh == 0) { s_gh0[row] = s0; s_gi1[row] = s1; s_gh1[row] = s2; }
        }
        __syncthreads();
        // P2: update h0[it] (lanes 0..63) and h1[it-1] (lanes 64..127)
        if (tid < GRUH) {
            if (it < TT) {
                const float ir = s_gi0[it*C1 + tid];
                const float iz = s_gi0[it*C1 + 64 + tid];
                const float in_ = s_gi0[it*C1 + 128 + tid];
                const float hr = s_gh0[tid], hz = s_gh0[64 + tid], hn = s_gh0[128 + tid];
                const float r = 1.f / (1.f + __expf(-(ir + hr)));
                const float z = 1.f / (1.f + __expf(-(iz + hz)));
                const float nx = in_ + r * hn;
                const float e2 = __expf(2.f * nx);
                const float n = (e2 - 1.f) / (e2 + 1.f);
                s_h0[tid] = (1.f - z) * n + z * s_h0[tid];
            }
        } else if (tid < 2 * GRUH) {
            if (it >= 1) {
                const int c = tid - GRUH;
                const float ir = s_gi1[c], iz = s_gi1[64 + c], in_ = s_gi1[128 + c];
                const float hr = s_gh1[c], hz = s_gh1[64 + c], hn = s_gh1[128 + c];
                const float r = 1.f / (1.f + __expf(-(ir + hr)));
                const float z = 1.f / (1.f + __expf(-(iz + hz)));
                const float nx = in_ + r * hn;
                const float e2 = __expf(2.f * nx);
                const float n = (e2 - 1.f) / (e2 + 1.f);
                s_h1[c] = (1.f - z) * n + z * s_h1[c];
            }
        }
        __syncthreads();
    }

    // ---- head: relu(h1[15] @ Wh1 + bh1) @ Wh2 + bh2 ----
    if (tid < 32) {
        float s = bh1[tid];
        #pragma unroll
        for (int k = 0; k < GRUH; k++) s += s_h1[k] * Wh1[k * 32 + tid];
        s_t1[tid] = fmaxf(s, 0.f);
    }
    __syncthreads();
    if (tid == 0) {
        float s = bh2[0];
        #pragma unroll
        for (int k = 0; k < 32; k++) s += s_t1[k] * Wh2[k];
        out[b] = s;
    }
}

extern "C" void kernel_launch(void* const* d_in, const int* in_sizes, int n_in,
                              void* d_out, int out_size, void* d_ws, size_t ws_size,
                              hipStream_t stream) {
    const float* x    = (const float*)d_in[0];
    // d_in[1] = edge_index, d_in[2] = batch : fixed dense structure -> unused
    const float* W1   = (const float*)d_in[3];
    const float* as1  = (const float*)d_in[4];
    const float* ad1  = (const float*)d_in[5];
    const float* b1   = (const float*)d_in[6];
    const float* W2   = (const float*)d_in[7];
    const float* as2  = (const float*)d_in[8];
    const float* ad2  = (const float*)d_in[9];
    const float* b2   = (const float*)d_in[10];
    const float* Wih0 = (const float*)d_in[11];
    const float* Whh0 = (const float*)d_in[12];
    const float* bih0 = (const float*)d_in[13];
    const float* bhh0 = (const float*)d_in[14];
    const float* Wih1 = (const float*)d_in[15];
    const float* Whh1 = (const float*)d_in[16];
    const float* bih1 = (const float*)d_in[17];
    const float* bhh1 = (const float*)d_in[18];
    const float* Wh1  = (const float*)d_in[19];
    const float* bh1  = (const float*)d_in[20];
    const float* Wh2  = (const float*)d_in[21];
    const float* bh2  = (const float*)d_in[22];

    float* out    = (float*)d_out;
    float* frames = (float*)d_ws;   // G x 96 fp32 = 393 KB

    hipLaunchKernelGGL(gat_fused, dim3(GG), dim3(256), 0, stream,
                       x, W1, as1, ad1, b1, W2, as2, ad2, b2, frames);
    hipLaunchKernelGGL(gru_head, dim3(BB), dim3(384), 0, stream,
                       frames, Wih0, bih0, Whh0, bhh0, Wih1, bih1, Whh1, bhh1,
                       Wh1, bh1, Wh2, bh2, out);
}

// Round 8
// 83.850 us; speedup vs baseline: 2.1148x; 1.1035x over previous
//
#include <hip/hip_runtime.h>
#include <math.h>

#define NPG    23
#define HID    48
#define HEADS  4
#define C1     192   // HEADS*HID
#define NFEAT  11
#define GG     1024  // B*T graphs
#define GRUH   64
#define FRAME  96
#define TT     16
#define BB     64

#define HSTR   196   // padded row stride for h/h1 (floats)
#define GSTR   52    // padded row stride for g

// LDS layout (floats), total 9456 = 37824 B -> 4 blocks/CU
// Region0 reused: x(253) -> als2(23)+ald2(23).
// H region reused: h(23*196) -> g(23*52) + h2(23*48).
#define OFF_X    0
#define OFF_ALS  256
#define OFF_ALD  348
#define OFF_H    440
#define OFF_H1   4948
#define LDSF     9456

__device__ __forceinline__ float elu_(float v) {
    return (v > 0.f) ? v : (__expf(v) - 1.f);
}

// ---------------------------------------------------------------------------
// Kernel 1: per-graph GAT1(4h)->ELU->GAT2->ELU->pool -> frames.
// 256 thr/block, 1024 blocks (4/CU via 37.9KB LDS, all co-resident).
// VGPR story (rounds 2-7): hipcc's cap = 256 / min_waves_per_EU.
//   (256,4) -> cap 64: spills any phase >64 live regs (68-300 MB scratch).
//   unbounded -> 200 VGPR: occupancy 10.7% (1 wave/SIMD), latency-bound.
//   (256,2) -> cap 128: fits all phases (~70 live max), HW still gives
//   4 waves/SIMD at <=128 VGPR (m69) = the LDS-allowed 4 blocks/CU.
// ---------------------------------------------------------------------------
__global__ __launch_bounds__(256, 2) void gat_fused(
    const float* __restrict__ x,      // NTOT x 11
    const float* __restrict__ W1,     // 11 x 192
    const float* __restrict__ as1,    // 192
    const float* __restrict__ ad1,    // 192
    const float* __restrict__ b1,     // 192
    const float* __restrict__ W2,     // 192 x 48
    const float* __restrict__ as2,    // 48
    const float* __restrict__ ad2,    // 48
    const float* __restrict__ b2,     // 48
    float* __restrict__ frames)       // G x 96
{
    __shared__ float S[LDSF];
    float* s_x    = S + OFF_X;
    float* s_als  = S + OFF_ALS;             // [hh*23+n]
    float* s_ald  = S + OFF_ALD;
    float* s_h    = S + OFF_H;               // 23 x 196
    float* s_h1   = S + OFF_H1;              // 23 x 196
    float* s_g    = S + OFF_H;               // overlays h (dead after E')
    float* s_h2   = S + OFF_H + NPG * GSTR;
    float* s_als2 = S + OFF_X;               // overlays x (dead after B)
    float* s_ald2 = S + OFF_X + NPG;

    const int g   = blockIdx.x;
    const int tid = threadIdx.x;

    // ---- phase 0: load x tile, zero als/ald ----
    for (int i = tid; i < NPG * NFEAT; i += 256) s_x[i] = x[g * NPG * NFEAT + i];
    if (tid < 184) s_als[tid] = 0.f;   // covers als+ald (contiguous 92+92)
    __syncthreads();

    // ---- phase 1: B+L1. h = x @ W1 (n-tile 5) + logit partial atomics ----
    if (tid < 240) {
        const int c4 = tid % 48, ng = tid / 48;
        const int hh = c4 / 12;
        const float4 a_s = *(const float4*)(as1 + 4 * c4);
        const float4 a_d = *(const float4*)(ad1 + 4 * c4);
        #pragma unroll
        for (int nn = 0; nn < 5; nn++) {
            const int n = ng * 5 + nn;
            if (n < NPG) {
                float4 acc = make_float4(0.f, 0.f, 0.f, 0.f);
                #pragma unroll
                for (int k = 0; k < NFEAT; k++) {
                    const float4 w = *(const float4*)(W1 + k * C1 + 4 * c4);
                    const float xv = s_x[n * NFEAT + k];
                    acc.x += xv * w.x; acc.y += xv * w.y;
                    acc.z += xv * w.z; acc.w += xv * w.w;
                }
                *(float4*)(s_h + n * HSTR + 4 * c4) = acc;
                atomicAdd(&s_als[hh * NPG + n],
                          acc.x * a_s.x + acc.y * a_s.y + acc.z * a_s.z + acc.w * a_s.w);
                atomicAdd(&s_ald[hh * NPG + n],
                          acc.x * a_d.x + acc.y * a_d.y + acc.z * a_d.z + acc.w * a_d.w);
            }
        }
    }
    __syncthreads();

    // ---- phase 2: E'. softmax1 (alpha in regs) + aggregate + b1 + ELU ----
    if (tid < 184) {
        const int j = tid >> 3, sub = tid & 7;
        const int hh = sub >> 1, half = sub & 1;
        const float ald_j = s_ald[hh * NPG + j];
        float a[NPG];
        float m = -1e30f;
        #pragma unroll
        for (int i = 0; i < NPG; i++) {
            float e = s_als[hh * NPG + i] + ald_j;
            e = (e > 0.f) ? e : 0.2f * e;
            a[i] = e;
            m = fmaxf(m, e);
        }
        float ssum = 0.f;
        #pragma unroll
        for (int i = 0; i < NPG; i++) {
            const float w = __expf(a[i] - m);
            a[i] = w;
            ssum += w;
        }
        const float inv = 1.f / (ssum + 1e-16f);
        const int cb = hh * HID + half * 24;
        #pragma unroll
        for (int c4 = 0; c4 < 6; c4++) {
            float4 acc = make_float4(0.f, 0.f, 0.f, 0.f);
            #pragma unroll
            for (int i = 0; i < NPG; i++) {
                const float4 hv = *(const float4*)(s_h + i * HSTR + cb + 4 * c4);
                acc.x += a[i] * hv.x; acc.y += a[i] * hv.y;
                acc.z += a[i] * hv.z; acc.w += a[i] * hv.w;
            }
            const float4 bb = *(const float4*)(b1 + cb + 4 * c4);
            float4 v;
            v.x = elu_(acc.x * inv + bb.x);
            v.y = elu_(acc.y * inv + bb.y);
            v.z = elu_(acc.z * inv + bb.z);
            v.w = elu_(acc.w * inv + bb.w);
            *(float4*)(s_h1 + j * HSTR + cb + 4 * c4) = v;
        }
    } else if (tid < 184 + 46) {
        s_als2[tid - 184] = 0.f;   // zero als2+ald2 (x region, dead after B)
    }
    __syncthreads();

    // ---- phase 3: F+L2. g = h1 @ W2, k-split 4 (low lane bits) x n-tile 6;
    //      shfl_xor(1,2) combines k-partials; W2 read 147 KB/block.
    //      Logit2 partial atomics folded in. ----
    if (tid < 192) {
        const int kc  = tid & 3;
        const int rem = tid >> 2;
        const int c4  = rem % 12, ng = rem / 12;   // ng 0..3, n-tile 6
        float4 acc[6];
        #pragma unroll
        for (int nn = 0; nn < 6; nn++) acc[nn] = make_float4(0.f, 0.f, 0.f, 0.f);
        #pragma unroll 2
        for (int k4 = 0; k4 < 12; k4++) {
            const int kk = kc * 12 + k4;
            const float* w2p = W2 + (4 * kk) * HID + 4 * c4;
            const float4 r0 = *(const float4*)(w2p);
            const float4 r1 = *(const float4*)(w2p + HID);
            const float4 r2 = *(const float4*)(w2p + 2 * HID);
            const float4 r3 = *(const float4*)(w2p + 3 * HID);
            #pragma unroll
            for (int nn = 0; nn < 6; nn++) {
                int n = ng * 6 + nn; n = (n < NPG) ? n : NPG - 1;
                const float4 hv = *(const float4*)(s_h1 + n * HSTR + 4 * kk);
                acc[nn].x += hv.x*r0.x + hv.y*r1.x + hv.z*r2.x + hv.w*r3.x;
                acc[nn].y += hv.x*r0.y + hv.y*r1.y + hv.z*r2.y + hv.w*r3.y;
                acc[nn].z += hv.x*r0.z + hv.y*r1.z + hv.z*r2.z + hv.w*r3.z;
                acc[nn].w += hv.x*r0.w + hv.y*r1.w + hv.z*r2.w + hv.w*r3.w;
            }
        }
        // combine the 4 k-partials (lanes differing in bits 0..1)
        #pragma unroll
        for (int nn = 0; nn < 6; nn++) {
            float4 a = acc[nn];
            a.x += __shfl_xor(a.x, 1); a.x += __shfl_xor(a.x, 2);
            a.y += __shfl_xor(a.y, 1); a.y += __shfl_xor(a.y, 2);
            a.z += __shfl_xor(a.z, 1); a.z += __shfl_xor(a.z, 2);
            a.w += __shfl_xor(a.w, 1); a.w += __shfl_xor(a.w, 2);
            acc[nn] = a;
        }
        if (kc == 0) {
            const float4 a_s = *(const float4*)(as2 + 4 * c4);
            const float4 a_d = *(const float4*)(ad2 + 4 * c4);
            #pragma unroll
            for (int nn = 0; nn < 6; nn++) {
                const int n = ng * 6 + nn;
                if (n < NPG) {
                    *(float4*)(s_g + n * GSTR + 4 * c4) = acc[nn];
                    atomicAdd(&s_als2[n],
                              acc[nn].x*a_s.x + acc[nn].y*a_s.y + acc[nn].z*a_s.z + acc[nn].w*a_s.w);
                    atomicAdd(&s_ald2[n],
                              acc[nn].x*a_d.x + acc[nn].y*a_d.y + acc[nn].z*a_d.z + acc[nn].w*a_d.w);
                }
            }
        }
    }
    __syncthreads();

    // ---- phase 4: H'. softmax2 + aggregate + b2 + ELU, j-tile 2 ----
    if (tid < 48) {
        const int q = tid & 3, jp = tid >> 2;
        const int j0 = 2 * jp, j1 = 2 * jp + 1;
        const bool has1 = (j1 < NPG);
        const int cb = q * 12;
        const float ald0 = s_ald2[j0];
        const float ald1 = has1 ? s_ald2[j1] : 0.f;
        float m0 = -1e30f, m1 = -1e30f;
        #pragma unroll
        for (int i = 0; i < NPG; i++) {
            const float ai = s_als2[i];
            float e0 = ai + ald0; e0 = (e0 > 0.f) ? e0 : 0.2f * e0;
            float e1 = ai + ald1; e1 = (e1 > 0.f) ? e1 : 0.2f * e1;
            m0 = fmaxf(m0, e0); m1 = fmaxf(m1, e1);
        }
        float4 acc0[3], acc1[3];
        #pragma unroll
        for (int c = 0; c < 3; c++) {
            acc0[c] = make_float4(0.f, 0.f, 0.f, 0.f);
            acc1[c] = make_float4(0.f, 0.f, 0.f, 0.f);
        }
        float ss0 = 0.f, ss1 = 0.f;
        #pragma unroll
        for (int i = 0; i < NPG; i++) {
            const float ai = s_als2[i];
            float e0 = ai + ald0; e0 = (e0 > 0.f) ? e0 : 0.2f * e0;
            float e1 = ai + ald1; e1 = (e1 > 0.f) ? e1 : 0.2f * e1;
            const float p0 = __expf(e0 - m0); ss0 += p0;
            const float p1 = __expf(e1 - m1); ss1 += p1;
            const float* gp = s_g + i * GSTR + cb;
            #pragma unroll
            for (int c = 0; c < 3; c++) {
                const float4 gv = *(const float4*)(gp + 4 * c);
                acc0[c].x += p0 * gv.x; acc0[c].y += p0 * gv.y;
                acc0[c].z += p0 * gv.z; acc0[c].w += p0 * gv.w;
                acc1[c].x += p1 * gv.x; acc1[c].y += p1 * gv.y;
                acc1[c].z += p1 * gv.z; acc1[c].w += p1 * gv.w;
            }
        }
        const float inv0 = 1.f / (ss0 + 1e-16f);
        const float inv1 = 1.f / (ss1 + 1e-16f);
        #pragma unroll
        for (int c = 0; c < 3; c++) {
            const float4 bb = *(const float4*)(b2 + cb + 4 * c);
            float4 v;
            v.x = elu_(acc0[c].x * inv0 + bb.x);
            v.y = elu_(acc0[c].y * inv0 + bb.y);
            v.z = elu_(acc0[c].z * inv0 + bb.z);
            v.w = elu_(acc0[c].w * inv0 + bb.w);
            *(float4*)(s_h2 + j0 * HID + cb + 4 * c) = v;
            if (has1) {
                v.x = elu_(acc1[c].x * inv1 + bb.x);
                v.y = elu_(acc1[c].y * inv1 + bb.y);
                v.z = elu_(acc1[c].z * inv1 + bb.z);
                v.w = elu_(acc1[c].w * inv1 + bb.w);
                *(float4*)(s_h2 + j1 * HID + cb + 4 * c) = v;
            }
        }
    }
    __syncthreads();

    // ---- phase 5: pool -> global frames ----
    if (tid < HID) {
        float sm = 0.f, mx = -1e30f;
        #pragma unroll
        for (int j = 0; j < NPG; j++) {
            const float v = s_h2[j * HID + tid];
            sm += v; mx = fmaxf(mx, v);
        }
        frames[g * FRAME + tid]       = sm * (1.0f / NPG);
        frames[g * FRAME + HID + tid] = mx;
    }
}

// ---------------------------------------------------------------------------
// Kernel 2: gi0 GEMM preamble + 2-layer GRU (T=16) + MLP head.
// 384 thr/block, 64 blocks. gi0 = frames @ Wih0^T computed here so Wih0 is
// read 64x (4.7 MB) instead of 1024x (75 MB). Recurrent loop: k-split-2
// pipeline (row=tid>>1, kh=tid&1, pair shfl; layer-1 one step behind
// layer-0; 2 barriers/step).
// ---------------------------------------------------------------------------
__global__ __launch_bounds__(384) void gru_head(
    const float* __restrict__ frames, // G x 96
    const float* __restrict__ Wih0,   // 192 x 96
    const float* __restrict__ bih0,   // 192
    const float* __restrict__ Whh0,   // 192 x 64
    const float* __restrict__ bhh0,
    const float* __restrict__ Wih1,   // 192 x 64
    const float* __restrict__ bih1,
    const float* __restrict__ Whh1,   // 192 x 64
    const float* __restrict__ bhh1,
    const float* __restrict__ Wh1,    // 64 x 32
    const float* __restrict__ bh1,
    const float* __restrict__ Wh2,    // 32 x 1
    const float* __restrict__ bh2,
    float* __restrict__ out)          // 64
{
    __shared__ float s_f[TT * FRAME];    // 1536
    __shared__ float s_gi0[TT * C1];     // 3072
    __shared__ float s_h0[GRUH], s_h1[GRUH];
    __shared__ float s_gh0[C1], s_gi1[C1], s_gh1[C1];
    __shared__ float s_t1[32];

    const int b = blockIdx.x, tid = threadIdx.x;

    {   // load this sequence's frames: 16x96 = 384 float4, 1 per thread
        const float4* src = (const float4*)(frames + b * TT * FRAME);
        ((float4*)s_f)[tid] = src[tid];
    }
    if (tid < GRUH) { s_h0[tid] = 0.f; s_h1[tid] = 0.f; }
    __syncthreads();

    // ---- gi0 preamble: gi0[t][c] = frame[t] . Wih0[c] + bih0[c] ----
    {
        const int c = tid % C1, tp = tid / C1;    // tp 0..1, 8 t's each
        float accg[8];
        const float b0 = bih0[c];
        #pragma unroll
        for (int tt = 0; tt < 8; tt++) accg[tt] = b0;
        const float4* wr = (const float4*)(Wih0 + c * FRAME);
        const float4* f4 = (const float4*)s_f;
        #pragma unroll 4
        for (int k4 = 0; k4 < FRAME / 4; k4++) {
            const float4 w = wr[k4];
            #pragma unroll
            for (int tt = 0; tt < 8; tt++) {
                const float4 f = f4[(tt * 2 + tp) * (FRAME / 4) + k4];
                accg[tt] += w.x * f.x + w.y * f.y + w.z * f.z + w.w * f.w;
            }
        }
        #pragma unroll
        for (int tt = 0; tt < 8; tt++) s_gi0[(tt * 2 + tp) * C1 + c] = accg[tt];
    }

    // ---- register-resident recurrent half-rows (3 x 32 floats) ----
    const int row = tid >> 1, kh = tid & 1;
    float w0[32], w1[32], w2[32];
    {
        const float4* p0 = (const float4*)(Whh0 + row * 64 + kh * 32);
        const float4* p1 = (const float4*)(Wih1 + row * 64 + kh * 32);
        const float4* p2 = (const float4*)(Whh1 + row * 64 + kh * 32);
        #pragma unroll
        for (int k4 = 0; k4 < 8; k4++) {
            const float4 v0 = p0[k4];
            w0[4*k4] = v0.x; w0[4*k4+1] = v0.y; w0[4*k4+2] = v0.z; w0[4*k4+3] = v0.w;
            const float4 v1 = p1[k4];
            w1[4*k4] = v1.x; w1[4*k4+1] = v1.y; w1[4*k4+2] = v1.z; w1[4*k4+3] = v1.w;
            const float4 v2 = p2[k4];
            w2[4*k4] = v2.x; w2[4*k4+1] = v2.y; w2[4*k4+2] = v2.z; w2[4*k4+3] = v2.w;
        }
    }
    const float bh0r = kh ? 0.f : bhh0[row];
    const float bi1r = kh ? 0.f : bih1[row];
    const float bh1r = kh ? 0.f : bhh1[row];
    __syncthreads();   // covers gi0 writes

    for (int it = 0; it <= TT; it++) {
        // P1: partial dots over this thread's k-half, pair-combine via shfl
        {
            float s0 = bh0r, s1 = bi1r, s2 = bh1r;
            const float4* h0v = (const float4*)(s_h0 + kh * 32);
            const float4* h1v = (const float4*)(s_h1 + kh * 32);
            #pragma unroll
            for (int k4 = 0; k4 < 8; k4++) {
                const float4 a = h0v[k4];
                const float4 c = h1v[k4];
                s0 += w0[4*k4]*a.x + w0[4*k4+1]*a.y + w0[4*k4+2]*a.z + w0[4*k4+3]*a.w;
                s1 += w1[4*k4]*a.x + w1[4*k4+1]*a.y + w1[4*k4+2]*a.z + w1[4*k4+3]*a.w;
                s2 += w2[4*k4]*c.x + w2[4*k4+1]*c.y + w2[4*k4+2]*c.z + w2[4*k4+3]*c.w;
            }
            s0 += __shfl_xor(s0, 1, 64);
            s1 += __shfl_xor(s1, 1, 64);
            s2 += __shfl_xor(s2, 1, 64);
            if (kh == 0) { s_gh0[row] = s0; s_gi1[row] = s1; s_gh1[row] = s2; }
        }
        __syncthreads();
        // P2: update h0[it] (lanes 0..63) and h1[it-1] (lanes 64..127)
        if (tid < GRUH) {
            if (it < TT) {
                const float ir = s_gi0[it*C1 + tid];
                const float iz = s_gi0[it*C1 + 64 + tid];
                const float in_ = s_gi0[it*C1 + 128 + tid];
                const float hr = s_gh0[tid], hz = s_gh0[64 + tid], hn = s_gh0[128 + tid];
                const float r = 1.f / (1.f + __expf(-(ir + hr)));
                const float z = 1.f / (1.f + __expf(-(iz + hz)));
                const float nx = in_ + r * hn;
                const float e2 = __expf(2.f * nx);
                const float n = (e2 - 1.f) / (e2 + 1.f);
                s_h0[tid] = (1.f - z) * n + z * s_h0[tid];
            }
        } else if (tid < 2 * GRUH) {
            if (it >= 1) {
                const int c = tid - GRUH;
                const float ir = s_gi1[c], iz = s_gi1[64 + c], in_ = s_gi1[128 + c];
                const float hr = s_gh1[c], hz = s_gh1[64 + c], hn = s_gh1[128 + c];
                const float r = 1.f / (1.f + __expf(-(ir + hr)));
                const float z = 1.f / (1.f + __expf(-(iz + hz)));
                const float nx = in_ + r * hn;
                const float e2 = __expf(2.f * nx);
                const float n = (e2 - 1.f) / (e2 + 1.f);
                s_h1[c] = (1.f - z) * n + z * s_h1[c];
            }
        }
        __syncthreads();
    }

    // ---- head: relu(h1[15] @ Wh1 + bh1) @ Wh2 + bh2 ----
    if (tid < 32) {
        float s = bh1[tid];
        #pragma unroll
        for (int k = 0; k < GRUH; k++) s += s_h1[k] * Wh1[k * 32 + tid];
        s_t1[tid] = fmaxf(s, 0.f);
    }
    __syncthreads();
    if (tid == 0) {
        float s = bh2[0];
        #pragma unroll
        for (int k = 0; k < 32; k++) s += s_t1[k] * Wh2[k];
        out[b] = s;
    }
}

extern "C" void kernel_launch(void* const* d_in, const int* in_sizes, int n_in,
                              void* d_out, int out_size, void* d_ws, size_t ws_size,
                              hipStream_t stream) {
    const float* x    = (const float*)d_in[0];
    // d_in[1] = edge_index, d_in[2] = batch : fixed dense structure -> unused
    const float* W1   = (const float*)d_in[3];
    const float* as1  = (const float*)d_in[4];
    const float* ad1  = (const float*)d_in[5];
    const float* b1   = (const float*)d_in[6];
    const float* W2   = (const float*)d_in[7];
    const float* as2  = (const float*)d_in[8];
    const float* ad2  = (const float*)d_in[9];
    const float* b2   = (const float*)d_in[10];
    const float* Wih0 = (const float*)d_in[11];
    const float* Whh0 = (const float*)d_in[12];
    const float* bih0 = (const float*)d_in[13];
    const float* bhh0 = (const float*)d_in[14];
    const float* Wih1 = (const float*)d_in[15];
    const float* Whh1 = (const float*)d_in[16];
    const float* bih1 = (const float*)d_in[17];
    const float* bhh1 = (const float*)d_in[18];
    const float* Wh1  = (const float*)d_in[19];
    const float* bh1  = (const float*)d_in[20];
    const float* Wh2  = (const float*)d_in[21];
    const float* bh2  = (const float*)d_in[22];

    float* out    = (float*)d_out;
    float* frames = (float*)d_ws;   // G x 96 fp32 = 393 KB

    hipLaunchKernelGGL(gat_fused, dim3(GG), dim3(256), 0, stream,
                       x, W1, as1, ad1, b1, W2, as2, ad2, b2, frames);
    hipLaunchKernelGGL(gru_head, dim3(BB), dim3(384), 0, stream,
                       frames, Wih0, bih0, Whh0, bhh0, Wih1, bih1, Whh1, bhh1,
                       Wh1, bh1, Wh2, bh2, out);
}

// Round 9
// 70.560 us; speedup vs baseline: 2.5131x; 1.1883x over previous
//
#include <hip/hip_runtime.h>
#include <math.h>

#define NPG    23
#define HID    48
#define HEADS  4
#define C1     192   // HEADS*HID
#define NFEAT  11
#define GG     1024  // B*T graphs
#define GRUH   64
#define FRAME  96
#define TT     16
#define BB     64

#define HSTR   196   // padded row stride for h/h1 (floats)
#define GSTR   52    // padded row stride for g

// LDS layout (floats), total 9456 = 37824 B -> 4 blocks/CU
#define OFF_X    0
#define OFF_ALS  256
#define OFF_ALD  348
#define OFF_H    440
#define OFF_H1   4948
#define LDSF     9456

__device__ __forceinline__ float elu_(float v) {
    return (v > 0.f) ? v : (__expf(v) - 1.f);
}

#define PHASE_FENCE() __builtin_amdgcn_sched_barrier(0)

// ---------------------------------------------------------------------------
// Kernel 1: per-graph GAT1(4h)->ELU->GAT2->ELU->pool -> frames.
// 256 thr/block, 1024 blocks (4/CU via 37.9KB LDS).
// Register discipline (rounds 3-8 lesson): cap = 256/min_waves = 128 via
// (256,2); DEMAND kept under the cap by (a) k-outer loop in B so W1/x loads
// are not hoistable en masse, (b) unroll-1 on big outer loops, (c)
// sched_barrier(0) between phases to stop cross-phase code motion.
// ---------------------------------------------------------------------------
__global__ __launch_bounds__(256, 2) void gat_fused(
    const float* __restrict__ x,      // NTOT x 11
    const float* __restrict__ W1,     // 11 x 192
    const float* __restrict__ as1,    // 192
    const float* __restrict__ ad1,    // 192
    const float* __restrict__ b1,     // 192
    const float* __restrict__ W2,     // 192 x 48
    const float* __restrict__ as2,    // 48
    const float* __restrict__ ad2,    // 48
    const float* __restrict__ b2,     // 48
    float* __restrict__ frames)       // G x 96
{
    __shared__ float S[LDSF];
    float* s_x    = S + OFF_X;
    float* s_als  = S + OFF_ALS;             // [hh*23+n]
    float* s_ald  = S + OFF_ALD;
    float* s_h    = S + OFF_H;               // 23 x 196
    float* s_h1   = S + OFF_H1;              // 23 x 196
    float* s_g    = S + OFF_H;               // overlays h (dead after E')
    float* s_h2   = S + OFF_H + NPG * GSTR;
    float* s_als2 = S + OFF_X;               // overlays x (dead after B)
    float* s_ald2 = S + OFF_X + NPG;

    const int g   = blockIdx.x;
    const int tid = threadIdx.x;

    // ---- phase 0: load x tile, zero als/ald ----
    for (int i = tid; i < NPG * NFEAT; i += 256) s_x[i] = x[g * NPG * NFEAT + i];
    if (tid < 184) s_als[tid] = 0.f;   // covers als+ald (contiguous 92+92)
    __syncthreads();
    PHASE_FENCE();

    // ---- phase 1: B+L1. h = x @ W1 (k-outer, n-tile 5) + logit atomics ----
    if (tid < 240) {
        const int c4 = tid % 48, ng = tid / 48;
        const int hh = c4 / 12;
        float4 acc[5];
        #pragma unroll
        for (int nn = 0; nn < 5; nn++) acc[nn] = make_float4(0.f, 0.f, 0.f, 0.f);
        #pragma unroll 1
        for (int k = 0; k < NFEAT; k++) {
            const float4 w = *(const float4*)(W1 + k * C1 + 4 * c4);
            #pragma unroll
            for (int nn = 0; nn < 5; nn++) {
                int n = ng * 5 + nn; n = (n < NPG) ? n : NPG - 1;
                const float xv = s_x[n * NFEAT + k];
                acc[nn].x += xv * w.x; acc[nn].y += xv * w.y;
                acc[nn].z += xv * w.z; acc[nn].w += xv * w.w;
            }
        }
        const float4 a_s = *(const float4*)(as1 + 4 * c4);
        const float4 a_d = *(const float4*)(ad1 + 4 * c4);
        #pragma unroll
        for (int nn = 0; nn < 5; nn++) {
            const int n = ng * 5 + nn;
            if (n < NPG) {
                *(float4*)(s_h + n * HSTR + 4 * c4) = acc[nn];
                atomicAdd(&s_als[hh * NPG + n],
                          acc[nn].x * a_s.x + acc[nn].y * a_s.y + acc[nn].z * a_s.z + acc[nn].w * a_s.w);
                atomicAdd(&s_ald[hh * NPG + n],
                          acc[nn].x * a_d.x + acc[nn].y * a_d.y + acc[nn].z * a_d.z + acc[nn].w * a_d.w);
            }
        }
    }
    __syncthreads();
    PHASE_FENCE();

    // ---- phase 2: E'. softmax1 (alpha in regs) + aggregate + b1 + ELU ----
    if (tid < 184) {
        const int j = tid >> 3, sub = tid & 7;
        const int hh = sub >> 1, half = sub & 1;
        const float ald_j = s_ald[hh * NPG + j];
        float a[NPG];
        float m = -1e30f;
        #pragma unroll
        for (int i = 0; i < NPG; i++) {
            float e = s_als[hh * NPG + i] + ald_j;
            e = (e > 0.f) ? e : 0.2f * e;
            a[i] = e;
            m = fmaxf(m, e);
        }
        float ssum = 0.f;
        #pragma unroll
        for (int i = 0; i < NPG; i++) {
            const float w = __expf(a[i] - m);
            a[i] = w;
            ssum += w;
        }
        const float inv = 1.f / (ssum + 1e-16f);
        const int cb = hh * HID + half * 24;
        #pragma unroll 1
        for (int c4 = 0; c4 < 6; c4++) {
            float4 acc = make_float4(0.f, 0.f, 0.f, 0.f);
            #pragma unroll
            for (int i = 0; i < NPG; i++) {
                const float4 hv = *(const float4*)(s_h + i * HSTR + cb + 4 * c4);
                acc.x += a[i] * hv.x; acc.y += a[i] * hv.y;
                acc.z += a[i] * hv.z; acc.w += a[i] * hv.w;
            }
            const float4 bb = *(const float4*)(b1 + cb + 4 * c4);
            float4 v;
            v.x = elu_(acc.x * inv + bb.x);
            v.y = elu_(acc.y * inv + bb.y);
            v.z = elu_(acc.z * inv + bb.z);
            v.w = elu_(acc.w * inv + bb.w);
            *(float4*)(s_h1 + j * HSTR + cb + 4 * c4) = v;
        }
    } else if (tid < 184 + 46) {
        s_als2[tid - 184] = 0.f;   // zero als2+ald2 (x region, dead after B)
    }
    __syncthreads();
    PHASE_FENCE();

    // ---- phase 3: F+L2. g = h1 @ W2, k-split 4 x n-tile 6, unroll-1 k4;
    //      shfl_xor(1,2) combines k-partials; logit2 atomics folded in ----
    if (tid < 192) {
        const int kc  = tid & 3;
        const int rem = tid >> 2;
        const int c4  = rem % 12, ng = rem / 12;   // ng 0..3, n-tile 6
        float4 acc[6];
        #pragma unroll
        for (int nn = 0; nn < 6; nn++) acc[nn] = make_float4(0.f, 0.f, 0.f, 0.f);
        #pragma unroll 1
        for (int k4 = 0; k4 < 12; k4++) {
            const int kk = kc * 12 + k4;
            const float* w2p = W2 + (4 * kk) * HID + 4 * c4;
            const float4 r0 = *(const float4*)(w2p);
            const float4 r1 = *(const float4*)(w2p + HID);
            const float4 r2 = *(const float4*)(w2p + 2 * HID);
            const float4 r3 = *(const float4*)(w2p + 3 * HID);
            #pragma unroll
            for (int nn = 0; nn < 6; nn++) {
                int n = ng * 6 + nn; n = (n < NPG) ? n : NPG - 1;
                const float4 hv = *(const float4*)(s_h1 + n * HSTR + 4 * kk);
                acc[nn].x += hv.x*r0.x + hv.y*r1.x + hv.z*r2.x + hv.w*r3.x;
                acc[nn].y += hv.x*r0.y + hv.y*r1.y + hv.z*r2.y + hv.w*r3.y;
                acc[nn].z += hv.x*r0.z + hv.y*r1.z + hv.z*r2.z + hv.w*r3.z;
                acc[nn].w += hv.x*r0.w + hv.y*r1.w + hv.z*r2.w + hv.w*r3.w;
            }
        }
        // combine the 4 k-partials (lanes differing in bits 0..1)
        #pragma unroll
        for (int nn = 0; nn < 6; nn++) {
            float4 a = acc[nn];
            a.x += __shfl_xor(a.x, 1); a.x += __shfl_xor(a.x, 2);
            a.y += __shfl_xor(a.y, 1); a.y += __shfl_xor(a.y, 2);
            a.z += __shfl_xor(a.z, 1); a.z += __shfl_xor(a.z, 2);
            a.w += __shfl_xor(a.w, 1); a.w += __shfl_xor(a.w, 2);
            acc[nn] = a;
        }
        if (kc == 0) {
            const float4 a_s = *(const float4*)(as2 + 4 * c4);
            const float4 a_d = *(const float4*)(ad2 + 4 * c4);
            #pragma unroll
            for (int nn = 0; nn < 6; nn++) {
                const int n = ng * 6 + nn;
                if (n < NPG) {
                    *(float4*)(s_g + n * GSTR + 4 * c4) = acc[nn];
                    atomicAdd(&s_als2[n],
                              acc[nn].x*a_s.x + acc[nn].y*a_s.y + acc[nn].z*a_s.z + acc[nn].w*a_s.w);
                    atomicAdd(&s_ald2[n],
                              acc[nn].x*a_d.x + acc[nn].y*a_d.y + acc[nn].z*a_d.z + acc[nn].w*a_d.w);
                }
            }
        }
    }
    __syncthreads();
    PHASE_FENCE();

    // ---- phase 4: H'. softmax2 + aggregate + b2 + ELU, j-tile 2 ----
    if (tid < 48) {
        const int q = tid & 3, jp = tid >> 2;
        const int j0 = 2 * jp, j1 = 2 * jp + 1;
        const bool has1 = (j1 < NPG);
        const int cb = q * 12;
        const float ald0 = s_ald2[j0];
        const float ald1 = has1 ? s_ald2[j1] : 0.f;
        float m0 = -1e30f, m1 = -1e30f;
        #pragma unroll
        for (int i = 0; i < NPG; i++) {
            const float ai = s_als2[i];
            float e0 = ai + ald0; e0 = (e0 > 0.f) ? e0 : 0.2f * e0;
            float e1 = ai + ald1; e1 = (e1 > 0.f) ? e1 : 0.2f * e1;
            m0 = fmaxf(m0, e0); m1 = fmaxf(m1, e1);
        }
        float4 acc0[3], acc1[3];
        #pragma unroll
        for (int c = 0; c < 3; c++) {
            acc0[c] = make_float4(0.f, 0.f, 0.f, 0.f);
            acc1[c] = make_float4(0.f, 0.f, 0.f, 0.f);
        }
        float ss0 = 0.f, ss1 = 0.f;
        #pragma unroll 1
        for (int i = 0; i < NPG; i++) {
            const float ai = s_als2[i];
            float e0 = ai + ald0; e0 = (e0 > 0.f) ? e0 : 0.2f * e0;
            float e1 = ai + ald1; e1 = (e1 > 0.f) ? e1 : 0.2f * e1;
            const float p0 = __expf(e0 - m0); ss0 += p0;
            const float p1 = __expf(e1 - m1); ss1 += p1;
            const float* gp = s_g + i * GSTR + cb;
            #pragma unroll
            for (int c = 0; c < 3; c++) {
                const float4 gv = *(const float4*)(gp + 4 * c);
                acc0[c].x += p0 * gv.x; acc0[c].y += p0 * gv.y;
                acc0[c].z += p0 * gv.z; acc0[c].w += p0 * gv.w;
                acc1[c].x += p1 * gv.x; acc1[c].y += p1 * gv.y;
                acc1[c].z += p1 * gv.z; acc1[c].w += p1 * gv.w;
            }
        }
        const float inv0 = 1.f / (ss0 + 1e-16f);
        const float inv1 = 1.f / (ss1 + 1e-16f);
        #pragma unroll
        for (int c = 0; c < 3; c++) {
            const float4 bb = *(const float4*)(b2 + cb + 4 * c);
            float4 v;
            v.x = elu_(acc0[c].x * inv0 + bb.x);
            v.y = elu_(acc0[c].y * inv0 + bb.y);
            v.z = elu_(acc0[c].z * inv0 + bb.z);
            v.w = elu_(acc0[c].w * inv0 + bb.w);
            *(float4*)(s_h2 + j0 * HID + cb + 4 * c) = v;
            if (has1) {
                v.x = elu_(acc1[c].x * inv1 + bb.x);
                v.y = elu_(acc1[c].y * inv1 + bb.y);
                v.z = elu_(acc1[c].z * inv1 + bb.z);
                v.w = elu_(acc1[c].w * inv1 + bb.w);
                *(float4*)(s_h2 + j1 * HID + cb + 4 * c) = v;
            }
        }
    }
    __syncthreads();
    PHASE_FENCE();

    // ---- phase 5: pool -> global frames ----
    if (tid < HID) {
        float sm = 0.f, mx = -1e30f;
        #pragma unroll
        for (int j = 0; j < NPG; j++) {
            const float v = s_h2[j * HID + tid];
            sm += v; mx = fmaxf(mx, v);
        }
        frames[g * FRAME + tid]       = sm * (1.0f / NPG);
        frames[g * FRAME + HID + tid] = mx;
    }
}

// ---------------------------------------------------------------------------
// Kernel 2: gi0 GEMM preamble + 2-layer GRU (T=16) + MLP head.
// 384 thr/block, 64 blocks. Recurrent loop: k-split-2 pipeline (row=tid>>1,
// kh=tid&1, pair shfl; layer-1 one step behind layer-0; 2 barriers/step).
// ---------------------------------------------------------------------------
__global__ __launch_bounds__(384) void gru_head(
    const float* __restrict__ frames, // G x 96
    const float* __restrict__ Wih0,   // 192 x 96
    const float* __restrict__ bih0,   // 192
    const float* __restrict__ Whh0,   // 192 x 64
    const float* __restrict__ bhh0,
    const float* __restrict__ Wih1,   // 192 x 64
    const float* __restrict__ bih1,
    const float* __restrict__ Whh1,   // 192 x 64
    const float* __restrict__ bhh1,
    const float* __restrict__ Wh1,    // 64 x 32
    const float* __restrict__ bh1,
    const float* __restrict__ Wh2,    // 32 x 1
    const float* __restrict__ bh2,
    float* __restrict__ out)          // 64
{
    __shared__ float s_f[TT * FRAME];    // 1536
    __shared__ float s_gi0[TT * C1];     // 3072
    __shared__ float s_h0[GRUH], s_h1[GRUH];
    __shared__ float s_gh0[C1], s_gi1[C1], s_gh1[C1];
    __shared__ float s_t1[32];

    const int b = blockIdx.x, tid = threadIdx.x;

    {   // load this sequence's frames: 16x96 = 384 float4, 1 per thread
        const float4* src = (const float4*)(frames + b * TT * FRAME);
        ((float4*)s_f)[tid] = src[tid];
    }
    if (tid < GRUH) { s_h0[tid] = 0.f; s_h1[tid] = 0.f; }
    __syncthreads();

    // ---- gi0 preamble: gi0[t][c] = frame[t] . Wih0[c] + bih0[c] ----
    {
        const int c = tid % C1, tp = tid / C1;    // tp 0..1, 8 t's each
        float accg[8];
        const float b0 = bih0[c];
        #pragma unroll
        for (int tt = 0; tt < 8; tt++) accg[tt] = b0;
        const float4* wr = (const float4*)(Wih0 + c * FRAME);
        const float4* f4 = (const float4*)s_f;
        #pragma unroll 4
        for (int k4 = 0; k4 < FRAME / 4; k4++) {
            const float4 w = wr[k4];
            #pragma unroll
            for (int tt = 0; tt < 8; tt++) {
                const float4 f = f4[(tt * 2 + tp) * (FRAME / 4) + k4];
                accg[tt] += w.x * f.x + w.y * f.y + w.z * f.z + w.w * f.w;
            }
        }
        #pragma unroll
        for (int tt = 0; tt < 8; tt++) s_gi0[(tt * 2 + tp) * C1 + c] = accg[tt];
    }

    // ---- register-resident recurrent half-rows (3 x 32 floats) ----
    const int row = tid >> 1, kh = tid & 1;
    float w0[32], w1[32], w2[32];
    {
        const float4* p0 = (const float4*)(Whh0 + row * 64 + kh * 32);
        const float4* p1 = (const float4*)(Wih1 + row * 64 + kh * 32);
        const float4* p2 = (const float4*)(Whh1 + row * 64 + kh * 32);
        #pragma unroll
        for (int k4 = 0; k4 < 8; k4++) {
            const float4 v0 = p0[k4];
            w0[4*k4] = v0.x; w0[4*k4+1] = v0.y; w0[4*k4+2] = v0.z; w0[4*k4+3] = v0.w;
            const float4 v1 = p1[k4];
            w1[4*k4] = v1.x; w1[4*k4+1] = v1.y; w1[4*k4+2] = v1.z; w1[4*k4+3] = v1.w;
            const float4 v2 = p2[k4];
            w2[4*k4] = v2.x; w2[4*k4+1] = v2.y; w2[4*k4+2] = v2.z; w2[4*k4+3] = v2.w;
        }
    }
    const float bh0r = kh ? 0.f : bhh0[row];
    const float bi1r = kh ? 0.f : bih1[row];
    const float bh1r = kh ? 0.f : bhh1[row];
    __syncthreads();   // covers gi0 writes

    for (int it = 0; it <= TT; it++) {
        // P1: partial dots over this thread's k-half, pair-combine via shfl
        {
            float s0 = bh0r, s1 = bi1r, s2 = bh1r;
            const float4* h0v = (const float4*)(s_h0 + kh * 32);
            const float4* h1v = (const float4*)(s_h1 + kh * 32);
            #pragma unroll
            for (int k4 = 0; k4 < 8; k4++) {
                const float4 a = h0v[k4];
                const float4 c = h1v[k4];
                s0 += w0[4*k4]*a.x + w0[4*k4+1]*a.y + w0[4*k4+2]*a.z + w0[4*k4+3]*a.w;
                s1 += w1[4*k4]*a.x + w1[4*k4+1]*a.y + w1[4*k4+2]*a.z + w1[4*k4+3]*a.w;
                s2 += w2[4*k4]*c.x + w2[4*k4+1]*c.y + w2[4*k4+2]*c.z + w2[4*k4+3]*c.w;
            }
            s0 += __shfl_xor(s0, 1, 64);
            s1 += __shfl_xor(s1, 1, 64);
            s2 += __shfl_xor(s2, 1, 64);
            if (kh == 0) { s_gh0[row] = s0; s_gi1[row] = s1; s_gh1[row] = s2; }
        }
        __syncthreads();
        // P2: update h0[it] (lanes 0..63) and h1[it-1] (lanes 64..127)
        if (tid < GRUH) {
            if (it < TT) {
                const float ir = s_gi0[it*C1 + tid];
                const float iz = s_gi0[it*C1 + 64 + tid];
                const float in_ = s_gi0[it*C1 + 128 + tid];
                const float hr = s_gh0[tid], hz = s_gh0[64 + tid], hn = s_gh0[128 + tid];
                const float r = 1.f / (1.f + __expf(-(ir + hr)));
                const float z = 1.f / (1.f + __expf(-(iz + hz)));
                const float nx = in_ + r * hn;
                const float e2 = __expf(2.f * nx);
                const float n = (e2 - 1.f) / (e2 + 1.f);
                s_h0[tid] = (1.f - z) * n + z * s_h0[tid];
            }
        } else if (tid < 2 * GRUH) {
            if (it >= 1) {
                const int c = tid - GRUH;
                const float ir = s_gi1[c], iz = s_gi1[64 + c], in_ = s_gi1[128 + c];
                const float hr = s_gh1[c], hz = s_gh1[64 + c], hn = s_gh1[128 + c];
                const float r = 1.f / (1.f + __expf(-(ir + hr)));
                const float z = 1.f / (1.f + __expf(-(iz + hz)));
                const float nx = in_ + r * hn;
                const float e2 = __expf(2.f * nx);
                const float n = (e2 - 1.f) / (e2 + 1.f);
                s_h1[c] = (1.f - z) * n + z * s_h1[c];
            }
        }
        __syncthreads();
    }

    // ---- head: relu(h1[15] @ Wh1 + bh1) @ Wh2 + bh2 ----
    if (tid < 32) {
        float s = bh1[tid];
        #pragma unroll
        for (int k = 0; k < GRUH; k++) s += s_h1[k] * Wh1[k * 32 + tid];
        s_t1[tid] = fmaxf(s, 0.f);
    }
    __syncthreads();
    if (tid == 0) {
        float s = bh2[0];
        #pragma unroll
        for (int k = 0; k < 32; k++) s += s_t1[k] * Wh2[k];
        out[b] = s;
    }
}

extern "C" void kernel_launch(void* const* d_in, const int* in_sizes, int n_in,
                              void* d_out, int out_size, void* d_ws, size_t ws_size,
                              hipStream_t stream) {
    const float* x    = (const float*)d_in[0];
    // d_in[1] = edge_index, d_in[2] = batch : fixed dense structure -> unused
    const float* W1   = (const float*)d_in[3];
    const float* as1  = (const float*)d_in[4];
    const float* ad1  = (const float*)d_in[5];
    const float* b1   = (const float*)d_in[6];
    const float* W2   = (const float*)d_in[7];
    const float* as2  = (const float*)d_in[8];
    const float* ad2  = (const float*)d_in[9];
    const float* b2   = (const float*)d_in[10];
    const float* Wih0 = (const float*)d_in[11];
    const float* Whh0 = (const float*)d_in[12];
    const float* bih0 = (const float*)d_in[13];
    const float* bhh0 = (const float*)d_in[14];
    const float* Wih1 = (const float*)d_in[15];
    const float* Whh1 = (const float*)d_in[16];
    const float* bih1 = (const float*)d_in[17];
    const float* bhh1 = (const float*)d_in[18];
    const float* Wh1  = (const float*)d_in[19];
    const float* bh1  = (const float*)d_in[20];
    const float* Wh2  = (const float*)d_in[21];
    const float* bh2  = (const float*)d_in[22];

    float* out    = (float*)d_out;
    float* frames = (float*)d_ws;   // G x 96 fp32 = 393 KB

    hipLaunchKernelGGL(gat_fused, dim3(GG), dim3(256), 0, stream,
                       x, W1, as1, ad1, b1, W2, as2, ad2, b2, frames);
    hipLaunchKernelGGL(gru_head, dim3(BB), dim3(384), 0, stream,
                       frames, Wih0, bih0, Whh0, bhh0, Wih1, bih1, Whh1, bhh1,
                       Wh1, bh1, Wh2, bh2, out);
}